// Round 2
// baseline (2988.747 us; speedup 1.0000x reference)
//
#include <hip/hip_runtime.h>
#include <hip/hip_bf16.h>
#include <math.h>
#include <stddef.h>

// Problem constants
#define BB 32
#define TT 262          // 256 vars + 6 marks
#define DD 512
#define SS 16
#define RR 32
#define SEQ 512
#define NV 256
#define PRED 96
#define MROWS (BB*TT)   // 8384

// ---------------------------------------------------------------------------
// 1) Per-(b,n) mean/stdev over SEQ time steps of x_enc (B,SEQ,NV)
// ---------------------------------------------------------------------------
__global__ __launch_bounds__(256)
void stats_kernel(const float* __restrict__ x_enc,
                  float* __restrict__ mean, float* __restrict__ stdv)
{
    int b  = blockIdx.x >> 2;
    int n0 = (blockIdx.x & 3) << 6;
    int lane = threadIdx.x & 63;
    int w    = threadIdx.x >> 6;
    int n = n0 + lane;
    float s = 0.f, s2 = 0.f;
    for (int t = w; t < SEQ; t += 4) {
        float v = x_enc[((size_t)b*SEQ + t)*NV + n];
        s += v; s2 += v*v;
    }
    __shared__ float ls[4][64], ls2[4][64];
    ls[w][lane] = s; ls2[w][lane] = s2;
    __syncthreads();
    if (w == 0) {
        s  = ls[0][lane] + ls[1][lane] + ls[2][lane] + ls[3][lane];
        s2 = ls2[0][lane] + ls2[1][lane] + ls2[2][lane] + ls2[3][lane];
        float mu  = s * (1.f/SEQ);
        float var = s2 * (1.f/SEQ) - mu*mu;
        mean[b*NV + n] = mu;
        stdv[b*NV + n] = sqrtf(var + 1e-5f);
    }
}

// ---------------------------------------------------------------------------
// 2) Build tok (B, TT, SEQ): normalized transpose of x_enc ++ transpose marks
// ---------------------------------------------------------------------------
__global__ __launch_bounds__(256)
void tok_kernel(const float* __restrict__ x_enc, const float* __restrict__ x_mark,
                const float* __restrict__ mean, const float* __restrict__ stdv,
                float* __restrict__ tok)
{
    int b  = blockIdx.x / 40;
    int r  = blockIdx.x % 40;
    int tt = r / 5;
    int vt = r % 5;
    int t0 = tt << 6, v0 = vt << 6;
    __shared__ float tile[64][65];
    int lv = threadIdx.x & 63;
    for (int i = threadIdx.x >> 6; i < 64; i += 4) {
        int t = t0 + i, v = v0 + lv;
        float val = 0.f;
        if (v < NV) {
            val = (x_enc[((size_t)b*SEQ + t)*NV + v] - mean[b*NV + v]) / stdv[b*NV + v];
        } else if (v < TT) {
            val = x_mark[((size_t)b*SEQ + t)*6 + (v - NV)];
        }
        tile[i][lv] = val;
    }
    __syncthreads();
    for (int i = threadIdx.x >> 6; i < 64; i += 4) {
        int v = v0 + i;
        if (v < TT)
            tok[((size_t)b*TT + v)*SEQ + t0 + lv] = tile[lv][i];
    }
}

// ---------------------------------------------------------------------------
// 3) fp32 GEMM: C[m,n] = sum_k A[m,k]*W[n,k] (+bias) (opt relu)
//    BM=BN=128, BK=8, 256 threads, per-thread 8x8 as split (4+4)x(4+4)
//    so LDS fragment reads are 16B-stride -> 2-way bank alias (free).
// ---------------------------------------------------------------------------
template<int ACT>   // 0 = none, 1 = relu
__global__ __launch_bounds__(256)
void gemm_nt(const float* __restrict__ A, int lda,
             const float* __restrict__ W,
             const float* __restrict__ bias,
             float* __restrict__ C, int ldc,
             int M, int N, int K)
{
    __shared__ float As[8][128];
    __shared__ float Bs[8][128];
    int m0 = blockIdx.x * 128;
    int n0 = blockIdx.y * 128;
    int tid = threadIdx.x;
    int lrow = tid >> 1, lseg = tid & 1;   // global-load mapping
    int tx = tid & 15, ty = tid >> 4;      // compute mapping

    int arow = m0 + lrow; if (arow >= M) arow = M - 1;
    int brow = n0 + lrow; if (brow >= N) brow = N - 1;
    const float* Ag = A + (size_t)arow*lda + lseg*4;
    const float* Wg = W + (size_t)brow*K   + lseg*4;

    float acc[8][8];
    #pragma unroll
    for (int i = 0; i < 8; ++i)
        #pragma unroll
        for (int j = 0; j < 8; ++j) acc[i][j] = 0.f;

    float4 aR = *(const float4*)Ag;
    float4 bR = *(const float4*)Wg;

    int nk = K >> 3;
    for (int kt = 0; kt < nk; ++kt) {
        As[lseg*4+0][lrow] = aR.x;
        As[lseg*4+1][lrow] = aR.y;
        As[lseg*4+2][lrow] = aR.z;
        As[lseg*4+3][lrow] = aR.w;
        Bs[lseg*4+0][lrow] = bR.x;
        Bs[lseg*4+1][lrow] = bR.y;
        Bs[lseg*4+2][lrow] = bR.z;
        Bs[lseg*4+3][lrow] = bR.w;
        __syncthreads();
        if (kt + 1 < nk) {
            aR = *(const float4*)(Ag + (kt+1)*8);
            bR = *(const float4*)(Wg + (kt+1)*8);
        }
        #pragma unroll
        for (int kk = 0; kk < 8; ++kk) {
            float af[8], bf[8];
            *(float4*)(af)   = *(const float4*)&As[kk][ty*4];
            *(float4*)(af+4) = *(const float4*)&As[kk][64 + ty*4];
            *(float4*)(bf)   = *(const float4*)&Bs[kk][tx*4];
            *(float4*)(bf+4) = *(const float4*)&Bs[kk][64 + tx*4];
            #pragma unroll
            for (int i = 0; i < 8; ++i)
                #pragma unroll
                for (int j = 0; j < 8; ++j)
                    acc[i][j] = fmaf(af[i], bf[j], acc[i][j]);
        }
        __syncthreads();
    }

    #pragma unroll
    for (int ih = 0; ih < 2; ++ih) {
        #pragma unroll
        for (int i = 0; i < 4; ++i) {
            int m = m0 + ih*64 + ty*4 + i;
            if (m >= M) continue;
            #pragma unroll
            for (int jh = 0; jh < 2; ++jh) {
                int n = n0 + jh*64 + tx*4;
                float v0 = acc[ih*4+i][jh*4+0];
                float v1 = acc[ih*4+i][jh*4+1];
                float v2 = acc[ih*4+i][jh*4+2];
                float v3 = acc[ih*4+i][jh*4+3];
                if (bias) {
                    if (n+3 < N) { v0 += bias[n]; v1 += bias[n+1]; v2 += bias[n+2]; v3 += bias[n+3]; }
                    else {
                        if (n   < N) v0 += bias[n];
                        if (n+1 < N) v1 += bias[n+1];
                        if (n+2 < N) v2 += bias[n+2];
                        if (n+3 < N) v3 += bias[n+3];
                    }
                }
                if (ACT == 1) {
                    v0 = fmaxf(v0, 0.f); v1 = fmaxf(v1, 0.f);
                    v2 = fmaxf(v2, 0.f); v3 = fmaxf(v3, 0.f);
                }
                if (n + 3 < N) {
                    float4 o; o.x=v0; o.y=v1; o.z=v2; o.w=v3;
                    *(float4*)&C[(size_t)m*ldc + n] = o;
                } else {
                    if (n   < N) C[(size_t)m*ldc + n  ] = v0;
                    if (n+1 < N) C[(size_t)m*ldc + n+1] = v1;
                    if (n+2 < N) C[(size_t)m*ldc + n+2] = v2;
                    if (n+3 < N) C[(size_t)m*ldc + n+3] = v3;
                }
            }
        }
    }
}

// ---------------------------------------------------------------------------
// 4) Depthwise width-2 conv + SiLU
// ---------------------------------------------------------------------------
__global__ __launch_bounds__(256)
void conv_silu(const float* __restrict__ xz, const float* __restrict__ cw,
               const float* __restrict__ cb, float* __restrict__ xc, int rev)
{
    int idx = blockIdx.x * 256 + threadIdx.x;       // over B*T*D (exact)
    int d  = idx & (DD-1);
    int bt = idx >> 9;
    int t  = bt % TT;
    float cur = xz[(size_t)bt*2*DD + d];
    int tn = rev ? t + 1 : t - 1;
    float prev = 0.f;
    if (tn >= 0 && tn < TT)
        prev = xz[((size_t)bt + (rev ? 1 : -1))*2*DD + d];
    float v = prev*cw[d*2] + cur*cw[d*2+1] + cb[d];
    xc[idx] = v / (1.f + __expf(-v));
}

// ---------------------------------------------------------------------------
// 5) Selective scan: one thread per (b,d,s). Depth-2 software prefetch with
//    named registers. 16-lane shfl reduce for the C-dot. grid=1024, block=256.
// ---------------------------------------------------------------------------
__global__ __launch_bounds__(256)
void scan_kernel(const float* __restrict__ dbl, const float* __restrict__ dtp,
                 const float* __restrict__ xc, const float* __restrict__ xz,
                 const float* __restrict__ alog, const float* __restrict__ dparam,
                 float* __restrict__ y, int rev)
{
    int g = blockIdx.x * 256 + threadIdx.x;
    int s = g & 15;
    int d = (g >> 4) & (DD-1);
    int b = g >> 13;

    float Acoef = -__expf(alog[d*SS + s]);
    float dp = dparam[d];
    float h = 0.f;
    int stp = rev ? -1 : 1;
    size_t bt = (size_t)b*TT + (rev ? TT-1 : 0);

#define LOADSET(off, dtv, xcv, zv, Bv, Cv) { \
        size_t p_ = bt + (size_t)((off)*stp); \
        dtv = dtp[p_*DD + d]; \
        xcv = xc[p_*DD + d]; \
        zv  = xz[p_*2*DD + DD + d]; \
        Bv  = dbl[p_*64 + RR + s]; \
        Cv  = dbl[p_*64 + RR + SS + s]; }

    float dtA, xcA, zA, BA, CA;
    float dtB, xcB, zB, BBv, CBv;
    LOADSET(0, dtA, xcA, zA, BA, CA);
    LOADSET(1, dtB, xcB, zB, BBv, CBv);

    for (int t = 0; t < TT; t += 2) {
        float dtN = 0.f, xcN = 0.f, zN = 0.f, BNv = 0.f, CNv = 0.f;
        if (t + 2 < TT) LOADSET(2, dtN, xcN, zN, BNv, CNv);
        // step t (A-set)
        {
            float sp = fmaxf(dtA, 0.f) + log1pf(__expf(-fabsf(dtA)));
            h = fmaf(__expf(sp*Acoef), h, sp*xcA*BA);
            float acc = h*CA;
            acc += __shfl_xor(acc, 1);
            acc += __shfl_xor(acc, 2);
            acc += __shfl_xor(acc, 4);
            acc += __shfl_xor(acc, 8);
            if (s == 0) {
                float sz = zA / (1.f + __expf(-zA));
                y[bt*DD + d] = (acc + dp*xcA) * sz;
            }
        }
        bt += stp;
        float dtM = 0.f, xcM = 0.f, zM = 0.f, BMv = 0.f, CMv = 0.f;
        if (t + 3 < TT) LOADSET(2, dtM, xcM, zM, BMv, CMv);
        // step t+1 (B-set)
        {
            float sp = fmaxf(dtB, 0.f) + log1pf(__expf(-fabsf(dtB)));
            h = fmaf(__expf(sp*Acoef), h, sp*xcB*BBv);
            float acc = h*CBv;
            acc += __shfl_xor(acc, 1);
            acc += __shfl_xor(acc, 2);
            acc += __shfl_xor(acc, 4);
            acc += __shfl_xor(acc, 8);
            if (s == 0) {
                float sz = zB / (1.f + __expf(-zB));
                y[bt*DD + d] = (acc + dp*xcB) * sz;
            }
        }
        bt += stp;
        dtA = dtN; xcA = xcN; zA = zN; BA = BNv; CA = CNv;
        dtB = dtM; xcB = xcM; zB = zM; BBv = BMv; CBv = CMv;
    }
#undef LOADSET
}

// ---------------------------------------------------------------------------
// 6) LayerNorm over D=512 with up to 3 summed inputs. One wave per row.
// ---------------------------------------------------------------------------
__global__ __launch_bounds__(64)
void ln_kernel(float* __restrict__ dst, const float* __restrict__ a,
               const float* __restrict__ b, const float* __restrict__ c,
               const float* __restrict__ g, const float* __restrict__ beta)
{
    int row = blockIdx.x;
    int lane = threadIdx.x;
    size_t base = (size_t)row * DD;
    float x[8];
    #pragma unroll
    for (int j = 0; j < 2; ++j) {
        int e4 = j*64 + lane;
        float4 v = *(const float4*)(a + base + (size_t)e4*4);
        if (b) { float4 t = *(const float4*)(b + base + (size_t)e4*4); v.x+=t.x; v.y+=t.y; v.z+=t.z; v.w+=t.w; }
        if (c) { float4 t = *(const float4*)(c + base + (size_t)e4*4); v.x+=t.x; v.y+=t.y; v.z+=t.z; v.w+=t.w; }
        x[j*4+0]=v.x; x[j*4+1]=v.y; x[j*4+2]=v.z; x[j*4+3]=v.w;
    }
    float s = 0.f;
    #pragma unroll
    for (int i = 0; i < 8; ++i) s += x[i];
    #pragma unroll
    for (int m = 1; m < 64; m <<= 1) s += __shfl_xor(s, m);
    float mu = s * (1.f/DD);
    float vs = 0.f;
    #pragma unroll
    for (int i = 0; i < 8; ++i) { float dd = x[i]-mu; vs += dd*dd; }
    #pragma unroll
    for (int m = 1; m < 64; m <<= 1) vs += __shfl_xor(vs, m);
    float r = rsqrtf(vs*(1.f/DD) + 1e-5f);
    #pragma unroll
    for (int j = 0; j < 2; ++j) {
        int e4 = j*64 + lane;
        float4 gv = *(const float4*)(g    + (size_t)e4*4);
        float4 bv = *(const float4*)(beta + (size_t)e4*4);
        float4 o;
        o.x = (x[j*4+0]-mu)*r*gv.x + bv.x;
        o.y = (x[j*4+1]-mu)*r*gv.y + bv.y;
        o.z = (x[j*4+2]-mu)*r*gv.z + bv.z;
        o.w = (x[j*4+3]-mu)*r*gv.w + bv.w;
        *(float4*)(dst + base + (size_t)e4*4) = o;
    }
}

// ---------------------------------------------------------------------------
// 7) Projection + transpose + de-normalization.
// ---------------------------------------------------------------------------
__global__ __launch_bounds__(128)
void proj_kernel(const float* __restrict__ hf, const float* __restrict__ pw,
                 const float* __restrict__ pb, const float* __restrict__ mean,
                 const float* __restrict__ stdv, float* __restrict__ out)
{
    int b  = blockIdx.x >> 5;
    int n0 = (blockIdx.x & 31) << 3;
    __shared__ float rows[8][DD];
    for (int i = threadIdx.x; i < 8*128; i += 128) {
        int rj = i >> 7, c4 = i & 127;
        ((float4*)rows[rj])[c4] =
            *(const float4*)(hf + ((size_t)b*TT + n0 + rj)*DD + (size_t)c4*4);
    }
    __syncthreads();
    int p = threadIdx.x;
    if (p < PRED) {
        float acc[8];
        #pragma unroll
        for (int j = 0; j < 8; ++j) acc[j] = 0.f;
        for (int k4 = 0; k4 < 128; ++k4) {
            float4 w = *(const float4*)(pw + (size_t)p*DD + (size_t)k4*4);
            #pragma unroll
            for (int j = 0; j < 8; ++j) {
                float4 rv = ((const float4*)rows[j])[k4];
                acc[j] += w.x*rv.x + w.y*rv.y + w.z*rv.z + w.w*rv.w;
            }
        }
        float bias = pb[p];
        #pragma unroll
        for (int j = 0; j < 8; ++j) {
            int n = n0 + j;
            out[((size_t)b*PRED + p)*NV + n] =
                (acc[j] + bias)*stdv[b*NV + n] + mean[b*NV + n];
        }
    }
}

// ---------------------------------------------------------------------------
extern "C" void kernel_launch(void* const* d_in, const int* in_sizes, int n_in,
                              void* d_out, int out_size, void* d_ws, size_t ws_size,
                              hipStream_t stream)
{
    (void)in_sizes; (void)n_in; (void)out_size; (void)ws_size;
    const float* x_enc   = (const float*)d_in[0];
    const float* x_mark  = (const float*)d_in[1];
    const float* emb_w   = (const float*)d_in[2];
    const float* emb_b   = (const float*)d_in[3];
    const float* m_win   = (const float*)d_in[4];
    const float* m_convw = (const float*)d_in[5];
    const float* m_convb = (const float*)d_in[6];
    const float* m_wx    = (const float*)d_in[7];
    const float* m_wdt   = (const float*)d_in[8];
    const float* m_bdt   = (const float*)d_in[9];
    const float* m_alog  = (const float*)d_in[10];
    const float* m_dpar  = (const float*)d_in[11];
    const float* m_wout  = (const float*)d_in[12];
    const float* ln1_g   = (const float*)d_in[13];
    const float* ln1_b   = (const float*)d_in[14];
    const float* ff1_w   = (const float*)d_in[15];
    const float* ff1_b   = (const float*)d_in[16];
    const float* ff2_w   = (const float*)d_in[17];
    const float* ff2_b   = (const float*)d_in[18];
    const float* ln2_g   = (const float*)d_in[19];
    const float* ln2_b   = (const float*)d_in[20];
    const float* lnf_g   = (const float*)d_in[21];
    const float* lnf_b   = (const float*)d_in[22];
    const float* proj_w  = (const float*)d_in[23];
    const float* proj_b  = (const float*)d_in[24];
    float* out = (float*)d_out;

    float* ws = (float*)d_ws;
    const size_t NBT = (size_t)MROWS;
    float* mean = ws;                    // 8192
    float* stdv = ws + 8192;             // 8192
    float* tok  = ws + 16384;            // NBT*512   (reused: ffn tmp, final LN)
    float* h    = tok  + NBT*DD;         // NBT*512
    float* xz   = h    + NBT*DD;         // NBT*1024
    float* xc   = xz   + NBT*2*DD;       // NBT*512
    float* dbl  = xc   + NBT*DD;         // NBT*64
    float* dtp  = dbl  + NBT*64;         // NBT*512
    float* ybuf = dtp  + NBT*DD;         // NBT*512
    float* fbuf = ybuf + NBT*DD;         // NBT*512
    float* rbuf = fbuf + NBT*DD;         // NBT*512

    stats_kernel<<<dim3(BB*4), 256, 0, stream>>>(x_enc, mean, stdv);
    tok_kernel<<<dim3(BB*40), 256, 0, stream>>>(x_enc, x_mark, mean, stdv, tok);

    // h = tok @ emb_w.T + emb_b
    gemm_nt<0><<<dim3(66,4), 256, 0, stream>>>(tok, SEQ, emb_w, emb_b, h, DD,
                                               MROWS, DD, SEQ);
    for (int l = 0; l < 2; ++l) {
        for (int dir = 0; dir < 2; ++dir) {
            int li = l*2 + dir;
            const float* win = m_win + (size_t)li*2*DD*DD;
            gemm_nt<0><<<dim3(66,8), 256, 0, stream>>>(h, DD, win, nullptr,
                                                       xz, 2*DD, MROWS, 2*DD, DD);
            conv_silu<<<dim3((MROWS*DD)/256), 256, 0, stream>>>(
                xz, m_convw + (size_t)li*DD*2, m_convb + (size_t)li*DD, xc, dir);
            gemm_nt<0><<<dim3(66,1), 256, 0, stream>>>(xc, DD,
                m_wx + (size_t)li*64*DD, nullptr, dbl, 64, MROWS, 64, DD);
            gemm_nt<0><<<dim3(66,4), 256, 0, stream>>>(dbl, 64,
                m_wdt + (size_t)li*DD*RR, m_bdt + (size_t)li*DD, dtp, DD,
                MROWS, DD, RR);
            scan_kernel<<<dim3(1024), 256, 0, stream>>>(dbl, dtp, xc, xz,
                m_alog + (size_t)li*DD*SS, m_dpar + (size_t)li*DD, ybuf, dir);
            float* mo = (dir == 0) ? fbuf : rbuf;
            gemm_nt<0><<<dim3(66,4), 256, 0, stream>>>(ybuf, DD,
                m_wout + (size_t)li*DD*DD, nullptr, mo, DD, MROWS, DD, DD);
        }
        ln_kernel<<<dim3(MROWS), 64, 0, stream>>>(h, h, fbuf, rbuf,
                                                  ln1_g + l*DD, ln1_b + l*DD);
        gemm_nt<1><<<dim3(66,4), 256, 0, stream>>>(h, DD,
            ff1_w + (size_t)l*DD*DD, ff1_b + l*DD, tok, DD, MROWS, DD, DD);
        gemm_nt<0><<<dim3(66,4), 256, 0, stream>>>(tok, DD,
            ff2_w + (size_t)l*DD*DD, ff2_b + l*DD, ybuf, DD, MROWS, DD, DD);
        ln_kernel<<<dim3(MROWS), 64, 0, stream>>>(h, h, ybuf, nullptr,
                                                  ln2_g + l*DD, ln2_b + l*DD);
    }
    ln_kernel<<<dim3(MROWS), 64, 0, stream>>>(tok, h, nullptr, nullptr, lnf_g, lnf_b);
    proj_kernel<<<dim3(BB*32), 128, 0, stream>>>(tok, proj_w, proj_b, mean, stdv, out);
}

// Round 3
// 2827.402 us; speedup vs baseline: 1.0571x; 1.0571x over previous
//
#include <hip/hip_runtime.h>
#include <hip/hip_bf16.h>
#include <math.h>
#include <stddef.h>

#define BB 32
#define TT 262
#define DD 512
#define SS 16
#define RR 32
#define SEQ 512
#define NV 256
#define PRED 96
#define MROWS (BB*TT)   // 8384

typedef __attribute__((ext_vector_type(4))) float f32x4;
typedef __attribute__((ext_vector_type(8))) short s16x8;

// ---------------- bf16 helpers ----------------
__device__ inline ushort f2bu(float x) {
    __hip_bfloat16 h = __float2bfloat16(x);
    ushort u; __builtin_memcpy(&u, &h, 2); return u;
}
__device__ inline float bu2f(ushort u) {
    __hip_bfloat16 h; __builtin_memcpy(&h, &u, 2);
    return __bfloat162float(h);
}
// activation 3K pack: [hi | lo | hi]
__device__ inline void pack_act(ushort* base, int col, int Kd, float v) {
    ushort hu = f2bu(v);
    float hf = bu2f(hu);
    ushort lu = f2bu(v - hf);
    base[col] = hu; base[Kd + col] = lu; base[2*Kd + col] = hu;
}

// ---------------------------------------------------------------------------
// weight 3K pack: [hi | hi | lo], K=512 rows
// ---------------------------------------------------------------------------
__global__ __launch_bounds__(256)
void pack3w(const float* __restrict__ in, ushort* __restrict__ out, int total)
{
    int idx = blockIdx.x * 256 + threadIdx.x;
    if (idx >= total) return;
    int r = idx >> 9, k = idx & 511;
    float x = in[idx];
    ushort hu = f2bu(x);
    float hf = bu2f(hu);
    ushort lu = f2bu(x - hf);
    size_t b = (size_t)r * 1536;
    out[b + k] = hu; out[b + 512 + k] = hu; out[b + 1024 + k] = lu;
}

// ---------------------------------------------------------------------------
// 1) per-(b,n) mean/std over SEQ
// ---------------------------------------------------------------------------
__global__ __launch_bounds__(256)
void stats_kernel(const float* __restrict__ x_enc,
                  float* __restrict__ mean, float* __restrict__ stdv)
{
    int b  = blockIdx.x >> 2;
    int n0 = (blockIdx.x & 3) << 6;
    int lane = threadIdx.x & 63;
    int w    = threadIdx.x >> 6;
    int n = n0 + lane;
    float s = 0.f, s2 = 0.f;
    for (int t = w; t < SEQ; t += 4) {
        float v = x_enc[((size_t)b*SEQ + t)*NV + n];
        s += v; s2 += v*v;
    }
    __shared__ float ls[4][64], ls2[4][64];
    ls[w][lane] = s; ls2[w][lane] = s2;
    __syncthreads();
    if (w == 0) {
        s  = ls[0][lane] + ls[1][lane] + ls[2][lane] + ls[3][lane];
        s2 = ls2[0][lane] + ls2[1][lane] + ls2[2][lane] + ls2[3][lane];
        float mu  = s * (1.f/SEQ);
        float var = s2 * (1.f/SEQ) - mu*mu;
        mean[b*NV + n] = mu;
        stdv[b*NV + n] = sqrtf(var + 1e-5f);
    }
}

// ---------------------------------------------------------------------------
// 2) tok3: normalized transpose packed [hi|lo|hi] over K=512
// ---------------------------------------------------------------------------
__global__ __launch_bounds__(256)
void tok_kernel(const float* __restrict__ x_enc, const float* __restrict__ x_mark,
                const float* __restrict__ mean, const float* __restrict__ stdv,
                ushort* __restrict__ tok3)
{
    int b  = blockIdx.x / 40;
    int r  = blockIdx.x % 40;
    int tt = r / 5;
    int vt = r % 5;
    int t0 = tt << 6, v0 = vt << 6;
    __shared__ float tile[64][65];
    int lv = threadIdx.x & 63;
    for (int i = threadIdx.x >> 6; i < 64; i += 4) {
        int t = t0 + i, v = v0 + lv;
        float val = 0.f;
        if (v < NV) {
            val = (x_enc[((size_t)b*SEQ + t)*NV + v] - mean[b*NV + v]) / stdv[b*NV + v];
        } else if (v < TT) {
            val = x_mark[((size_t)b*SEQ + t)*6 + (v - NV)];
        }
        tile[i][lv] = val;
    }
    __syncthreads();
    for (int i = threadIdx.x >> 6; i < 64; i += 4) {
        int v = v0 + i;
        if (v < TT) {
            size_t row = (size_t)b*TT + v;
            pack_act(tok3 + row*1536, t0 + lv, 512, tile[lv][i]);
        }
    }
}

// ---------------------------------------------------------------------------
// 3) bf16 MFMA GEMM over packed 3K operands.
//    C[m,n] = sum_k3 A3[m,k3]*W3[n,k3]  (NT, both row-major, K3 mult of 64)
//    tile 128x128, BK=64, 256 threads (4 waves 2x2), reg-staged LDS with
//    XOR swizzle; optional bias/relu; writes fp32 C and/or 3K-packed bf16 C3.
// ---------------------------------------------------------------------------
template<int HAS_BIAS, int RELU, int WF32, int W3>
__global__ __launch_bounds__(256, 2)
void gemm3(const ushort* __restrict__ A3, int lda3,
           const ushort* __restrict__ W3p, int ldw3,
           const float* __restrict__ bias,
           float* __restrict__ C, int ldc,
           ushort* __restrict__ C3, int N_out,
           int M, int K3)
{
    __shared__ ushort As[128*64];
    __shared__ ushort Ws[128*64];
    int m0 = blockIdx.x * 128;
    int n0 = blockIdx.y * 128;
    int tid = threadIdx.x;
    int lane = tid & 63;
    int wid  = tid >> 6;
    int wr = wid >> 1, wc = wid & 1;

    // staging coords: 4 chunks of 16B each for A and W
    int st_row[4], st_sl[4], st_dst[4];
    #pragma unroll
    for (int q = 0; q < 4; ++q) {
        int sid = q*256 + tid;
        int r = sid >> 3, sl = sid & 7;
        st_row[q] = r; st_sl[q] = sl;
        st_dst[q] = r*128 + ((sl ^ (r & 7)) << 4);   // byte offset, swizzled
    }

    f32x4 acc[4][4];
    #pragma unroll
    for (int i = 0; i < 4; ++i)
        #pragma unroll
        for (int j = 0; j < 4; ++j) acc[i][j] = (f32x4){0.f,0.f,0.f,0.f};

    int nk = K3 >> 6;
    uint4 pa[4], pw[4];
    #pragma unroll
    for (int q = 0; q < 4; ++q) {
        int ar = m0 + st_row[q]; if (ar >= M) ar = M - 1;
        pa[q] = *(const uint4*)(A3 + (size_t)ar*lda3 + st_sl[q]*8);
        int wrow = n0 + st_row[q];
        pw[q] = *(const uint4*)(W3p + (size_t)wrow*ldw3 + st_sl[q]*8);
    }

    int rl = lane & 15;          // fragment row/col within 16
    int kq = lane >> 4;          // k-quarter
    int r7a = rl & 7;

    for (int kt = 0; kt < nk; ++kt) {
        __syncthreads();
        #pragma unroll
        for (int q = 0; q < 4; ++q) {
            *(uint4*)((char*)As + st_dst[q]) = pa[q];
            *(uint4*)((char*)Ws + st_dst[q]) = pw[q];
        }
        if (kt + 1 < nk) {
            #pragma unroll
            for (int q = 0; q < 4; ++q) {
                int ar = m0 + st_row[q]; if (ar >= M) ar = M - 1;
                pa[q] = *(const uint4*)(A3 + (size_t)ar*lda3 + (kt+1)*64 + st_sl[q]*8);
                int wrow = n0 + st_row[q];
                pw[q] = *(const uint4*)(W3p + (size_t)wrow*ldw3 + (kt+1)*64 + st_sl[q]*8);
            }
        }
        __syncthreads();
        #pragma unroll
        for (int kk = 0; kk < 2; ++kk) {
            s16x8 av[4], wv[4];
            #pragma unroll
            for (int mi = 0; mi < 4; ++mi) {
                int row = wr*64 + mi*16 + rl;
                int slot = (kk*4 + kq) ^ (row & 7);
                av[mi] = *(const s16x8*)((const char*)As + row*128 + (slot<<4));
            }
            #pragma unroll
            for (int ni = 0; ni < 4; ++ni) {
                int row = wc*64 + ni*16 + rl;
                int slot = (kk*4 + kq) ^ (row & 7);
                wv[ni] = *(const s16x8*)((const char*)Ws + row*128 + (slot<<4));
            }
            #pragma unroll
            for (int mi = 0; mi < 4; ++mi)
                #pragma unroll
                for (int ni = 0; ni < 4; ++ni)
                    acc[mi][ni] = __builtin_amdgcn_mfma_f32_16x16x32_bf16(
                        av[mi], wv[ni], acc[mi][ni], 0, 0, 0);
        }
    }
    (void)r7a;

    // epilogue: D col = lane&15, row = (lane>>4)*4 + j
    #pragma unroll
    for (int ni = 0; ni < 4; ++ni) {
        int n = n0 + wc*64 + ni*16 + rl;
        float bv = HAS_BIAS ? bias[n] : 0.f;
        #pragma unroll
        for (int mi = 0; mi < 4; ++mi) {
            #pragma unroll
            for (int j = 0; j < 4; ++j) {
                int m = m0 + wr*64 + mi*16 + kq*4 + j;
                if (m >= M) continue;
                float v = acc[mi][ni][j];
                if (HAS_BIAS) v += bv;
                if (RELU) v = fmaxf(v, 0.f);
                if (WF32) C[(size_t)m*ldc + n] = v;
                if (W3)   pack_act(C3 + (size_t)m*(3*N_out), n, N_out, v);
            }
        }
    }
}

// ---------------------------------------------------------------------------
// 4) fp32 GEMM (kept for wx / wdt). ACT: 0 none, 2 softplus.
// ---------------------------------------------------------------------------
template<int ACT>
__global__ __launch_bounds__(256)
void gemm_nt(const float* __restrict__ A, int lda,
             const float* __restrict__ W,
             const float* __restrict__ bias,
             float* __restrict__ C, int ldc,
             int M, int N, int K)
{
    __shared__ float Asl[8][128];
    __shared__ float Bsl[8][128];
    int m0 = blockIdx.x * 128;
    int n0 = blockIdx.y * 128;
    int tid = threadIdx.x;
    int lrow = tid >> 1, lseg = tid & 1;
    int tx = tid & 15, ty = tid >> 4;

    int arow = m0 + lrow; if (arow >= M) arow = M - 1;
    int brow = n0 + lrow; if (brow >= N) brow = N - 1;
    const float* Ag = A + (size_t)arow*lda + lseg*4;
    const float* Wg = W + (size_t)brow*K   + lseg*4;

    float acc[8][8];
    #pragma unroll
    for (int i = 0; i < 8; ++i)
        #pragma unroll
        for (int j = 0; j < 8; ++j) acc[i][j] = 0.f;

    float4 aR = *(const float4*)Ag;
    float4 bR = *(const float4*)Wg;

    int nk = K >> 3;
    for (int kt = 0; kt < nk; ++kt) {
        Asl[lseg*4+0][lrow] = aR.x; Asl[lseg*4+1][lrow] = aR.y;
        Asl[lseg*4+2][lrow] = aR.z; Asl[lseg*4+3][lrow] = aR.w;
        Bsl[lseg*4+0][lrow] = bR.x; Bsl[lseg*4+1][lrow] = bR.y;
        Bsl[lseg*4+2][lrow] = bR.z; Bsl[lseg*4+3][lrow] = bR.w;
        __syncthreads();
        if (kt + 1 < nk) {
            aR = *(const float4*)(Ag + (kt+1)*8);
            bR = *(const float4*)(Wg + (kt+1)*8);
        }
        #pragma unroll
        for (int kk = 0; kk < 8; ++kk) {
            float af[8], bf[8];
            *(float4*)(af)   = *(const float4*)&Asl[kk][ty*4];
            *(float4*)(af+4) = *(const float4*)&Asl[kk][64 + ty*4];
            *(float4*)(bf)   = *(const float4*)&Bsl[kk][tx*4];
            *(float4*)(bf+4) = *(const float4*)&Bsl[kk][64 + tx*4];
            #pragma unroll
            for (int i = 0; i < 8; ++i)
                #pragma unroll
                for (int j = 0; j < 8; ++j)
                    acc[i][j] = fmaf(af[i], bf[j], acc[i][j]);
        }
        __syncthreads();
    }

    #pragma unroll
    for (int ih = 0; ih < 2; ++ih) {
        #pragma unroll
        for (int i = 0; i < 4; ++i) {
            int m = m0 + ih*64 + ty*4 + i;
            if (m >= M) continue;
            #pragma unroll
            for (int jh = 0; jh < 2; ++jh) {
                int n = n0 + jh*64 + tx*4;
                if (n >= N) continue;
                #pragma unroll
                for (int jj = 0; jj < 4; ++jj) {
                    float v = acc[ih*4+i][jh*4+jj];
                    if (bias) v += bias[n+jj];
                    if (ACT == 2) v = fmaxf(v, 0.f) + log1pf(__expf(-fabsf(v)));
                    C[(size_t)m*ldc + n + jj] = v;
                }
            }
        }
    }
}

// ---------------------------------------------------------------------------
// 5) conv + SiLU, and in-place silu on z-half of xz
// ---------------------------------------------------------------------------
__global__ __launch_bounds__(256)
void conv_silu(float* __restrict__ xz, const float* __restrict__ cw,
               const float* __restrict__ cb, float* __restrict__ xc, int rev)
{
    int idx = blockIdx.x * 256 + threadIdx.x;
    int d  = idx & (DD-1);
    int bt = idx >> 9;
    int t  = bt % TT;
    float cur = xz[(size_t)bt*2*DD + d];
    int tn = rev ? t + 1 : t - 1;
    float prev = 0.f;
    if (tn >= 0 && tn < TT)
        prev = xz[((size_t)bt + (rev ? 1 : -1))*2*DD + d];
    float v = prev*cw[d*2] + cur*cw[d*2+1] + cb[d];
    xc[idx] = v / (1.f + __expf(-v));
    float z = xz[(size_t)bt*2*DD + DD + d];
    xz[(size_t)bt*2*DD + DD + d] = z / (1.f + __expf(-z));
}

// ---------------------------------------------------------------------------
// 6) Scan V2: LDS-chunked. block=(b, 64 d), 256 thr = 64 d x 4 s-groups.
//    sp precomputed (softplus), zs = silu(z) in-place in xz z-half.
//    Writes y packed [hi|lo|hi] into y3.
// ---------------------------------------------------------------------------
#define CH 32
__global__ __launch_bounds__(256)
void scan2(const float* __restrict__ sp_g, const float* __restrict__ xc_g,
           const float* __restrict__ xz_g, const float* __restrict__ dbl_g,
           const float* __restrict__ alog, const float* __restrict__ dparam,
           ushort* __restrict__ y3, int rev)
{
    int b  = blockIdx.x >> 3;
    int d0 = (blockIdx.x & 7) << 6;
    int tid = threadIdx.x;
    int sg = tid & 3;
    int dl = tid >> 2;
    int d  = d0 + dl;

    __shared__ float t_sp[CH][68], t_xc[CH][68], t_zs[CH][68], t_bc[CH][36];

    float Ac[4];
    #pragma unroll
    for (int j = 0; j < 4; ++j)
        Ac[j] = -__expf(alog[d*SS + sg*4 + j]);
    float dp = dparam[d];
    float h0=0.f, h1=0.f, h2=0.f, h3=0.f;
    size_t bbase = (size_t)b*TT;

    // staging map
    int r_a = tid >> 4, c_a = (tid & 15) << 2;         // arrays: f4 id tid, tid+256
    int r_a2 = (tid + 256) >> 4, c_a2 = ((tid + 256) & 15) << 2;
    int r_b = tid >> 3, c_b = (tid & 7) << 2;          // bc tile

#define GROW(tg_) (rev ? (TT-1-(tg_)) : (tg_))
#define LOADCH(c_, s0,s1, x0,x1, z0,z1, bc0) { \
        int tgA = (c_)*CH + r_a;  if (tgA > TT-1) tgA = TT-1; \
        int tgB = (c_)*CH + r_a2; if (tgB > TT-1) tgB = TT-1; \
        int tgC = (c_)*CH + r_b;  if (tgC > TT-1) tgC = TT-1; \
        size_t pA = bbase + GROW(tgA), pB = bbase + GROW(tgB), pC = bbase + GROW(tgC); \
        s0 = *(const float4*)(sp_g + pA*DD + d0 + c_a); \
        s1 = *(const float4*)(sp_g + pB*DD + d0 + c_a2); \
        x0 = *(const float4*)(xc_g + pA*DD + d0 + c_a); \
        x1 = *(const float4*)(xc_g + pB*DD + d0 + c_a2); \
        z0 = *(const float4*)(xz_g + pA*2*DD + DD + d0 + c_a); \
        z1 = *(const float4*)(xz_g + pB*2*DD + DD + d0 + c_a2); \
        bc0 = *(const float4*)(dbl_g + pC*64 + 32 + c_b); }

    float4 s0,s1,x0,x1,z0,z1,bc0;
    LOADCH(0, s0,s1,x0,x1,z0,z1,bc0);

    const int nch = (TT + CH - 1) / CH;
    for (int c = 0; c < nch; ++c) {
        __syncthreads();
        *(float4*)&t_sp[r_a ][c_a ] = s0;
        *(float4*)&t_sp[r_a2][c_a2] = s1;
        *(float4*)&t_xc[r_a ][c_a ] = x0;
        *(float4*)&t_xc[r_a2][c_a2] = x1;
        *(float4*)&t_zs[r_a ][c_a ] = z0;
        *(float4*)&t_zs[r_a2][c_a2] = z1;
        *(float4*)&t_bc[r_b ][c_b ] = bc0;
        if (c + 1 < nch)
            LOADCH(c+1, s0,s1,x0,x1,z0,z1,bc0);
        __syncthreads();

        int steps = TT - c*CH; if (steps > CH) steps = CH;
        for (int i = 0; i < steps; ++i) {
            float spv = t_sp[i][dl];
            float xcv = t_xc[i][dl];
            float4 Bv = *(const float4*)&t_bc[i][sg*4];
            float4 Cv = *(const float4*)&t_bc[i][16 + sg*4];
            float dtxc = spv * xcv;
            h0 = fmaf(__expf(spv*Ac[0]), h0, dtxc*Bv.x);
            h1 = fmaf(__expf(spv*Ac[1]), h1, dtxc*Bv.y);
            h2 = fmaf(__expf(spv*Ac[2]), h2, dtxc*Bv.z);
            h3 = fmaf(__expf(spv*Ac[3]), h3, dtxc*Bv.w);
            float dot = h0*Cv.x + h1*Cv.y + h2*Cv.z + h3*Cv.w;
            dot += __shfl_xor(dot, 1);
            dot += __shfl_xor(dot, 2);
            if (sg == 0) {
                int t = GROW(c*CH + i);
                float yv = (dot + dp*xcv) * t_zs[i][dl];
                pack_act(y3 + (bbase + t)*1536, d, 512, yv);
            }
        }
    }
#undef LOADCH
#undef GROW
}

// ---------------------------------------------------------------------------
// 7) LayerNorm (up to 3 summed inputs), optional 3K-pack output
// ---------------------------------------------------------------------------
__global__ __launch_bounds__(64)
void ln_kernel(float* __restrict__ dst, const float* __restrict__ a,
               const float* __restrict__ b, const float* __restrict__ c,
               const float* __restrict__ g, const float* __restrict__ beta,
               ushort* __restrict__ out3)
{
    int row = blockIdx.x;
    int lane = threadIdx.x;
    size_t base = (size_t)row * DD;
    float x[8];
    #pragma unroll
    for (int j = 0; j < 2; ++j) {
        int e4 = j*64 + lane;
        float4 v = *(const float4*)(a + base + (size_t)e4*4);
        if (b) { float4 t = *(const float4*)(b + base + (size_t)e4*4); v.x+=t.x; v.y+=t.y; v.z+=t.z; v.w+=t.w; }
        if (c) { float4 t = *(const float4*)(c + base + (size_t)e4*4); v.x+=t.x; v.y+=t.y; v.z+=t.z; v.w+=t.w; }
        x[j*4+0]=v.x; x[j*4+1]=v.y; x[j*4+2]=v.z; x[j*4+3]=v.w;
    }
    float s = 0.f;
    #pragma unroll
    for (int i = 0; i < 8; ++i) s += x[i];
    #pragma unroll
    for (int m = 1; m < 64; m <<= 1) s += __shfl_xor(s, m);
    float mu = s * (1.f/DD);
    float vs = 0.f;
    #pragma unroll
    for (int i = 0; i < 8; ++i) { float dd = x[i]-mu; vs += dd*dd; }
    #pragma unroll
    for (int m = 1; m < 64; m <<= 1) vs += __shfl_xor(vs, m);
    float r = rsqrtf(vs*(1.f/DD) + 1e-5f);
    #pragma unroll
    for (int j = 0; j < 2; ++j) {
        int e4 = j*64 + lane;
        float4 gv = *(const float4*)(g    + (size_t)e4*4);
        float4 bv = *(const float4*)(beta + (size_t)e4*4);
        float4 o;
        o.x = (x[j*4+0]-mu)*r*gv.x + bv.x;
        o.y = (x[j*4+1]-mu)*r*gv.y + bv.y;
        o.z = (x[j*4+2]-mu)*r*gv.z + bv.z;
        o.w = (x[j*4+3]-mu)*r*gv.w + bv.w;
        *(float4*)(dst + base + (size_t)e4*4) = o;
        if (out3) {
            ushort* ob = out3 + (size_t)row*1536;
            pack_act(ob, e4*4+0, 512, o.x);
            pack_act(ob, e4*4+1, 512, o.y);
            pack_act(ob, e4*4+2, 512, o.z);
            pack_act(ob, e4*4+3, 512, o.w);
        }
    }
}

// ---------------------------------------------------------------------------
// 8) projection + transpose + de-norm
// ---------------------------------------------------------------------------
__global__ __launch_bounds__(128)
void proj_kernel(const float* __restrict__ hf, const float* __restrict__ pw,
                 const float* __restrict__ pb, const float* __restrict__ mean,
                 const float* __restrict__ stdv, float* __restrict__ out)
{
    int b  = blockIdx.x >> 5;
    int n0 = (blockIdx.x & 31) << 3;
    __shared__ float rows[8][DD];
    for (int i = threadIdx.x; i < 8*128; i += 128) {
        int rj = i >> 7, c4 = i & 127;
        ((float4*)rows[rj])[c4] =
            *(const float4*)(hf + ((size_t)b*TT + n0 + rj)*DD + (size_t)c4*4);
    }
    __syncthreads();
    int p = threadIdx.x;
    if (p < PRED) {
        float acc[8];
        #pragma unroll
        for (int j = 0; j < 8; ++j) acc[j] = 0.f;
        for (int k4 = 0; k4 < 128; ++k4) {
            float4 w = *(const float4*)(pw + (size_t)p*DD + (size_t)k4*4);
            #pragma unroll
            for (int j = 0; j < 8; ++j) {
                float4 rv = ((const float4*)rows[j])[k4];
                acc[j] += w.x*rv.x + w.y*rv.y + w.z*rv.z + w.w*rv.w;
            }
        }
        float bias = pb[p];
        #pragma unroll
        for (int j = 0; j < 8; ++j) {
            int n = n0 + j;
            out[((size_t)b*PRED + p)*NV + n] =
                (acc[j] + bias)*stdv[b*NV + n] + mean[b*NV + n];
        }
    }
}

// ---------------------------------------------------------------------------
extern "C" void kernel_launch(void* const* d_in, const int* in_sizes, int n_in,
                              void* d_out, int out_size, void* d_ws, size_t ws_size,
                              hipStream_t stream)
{
    (void)in_sizes; (void)n_in; (void)out_size; (void)ws_size;
    const float* x_enc   = (const float*)d_in[0];
    const float* x_mark  = (const float*)d_in[1];
    const float* emb_w   = (const float*)d_in[2];
    const float* emb_b   = (const float*)d_in[3];
    const float* m_win   = (const float*)d_in[4];
    const float* m_convw = (const float*)d_in[5];
    const float* m_convb = (const float*)d_in[6];
    const float* m_wx    = (const float*)d_in[7];
    const float* m_wdt   = (const float*)d_in[8];
    const float* m_bdt   = (const float*)d_in[9];
    const float* m_alog  = (const float*)d_in[10];
    const float* m_dpar  = (const float*)d_in[11];
    const float* m_wout  = (const float*)d_in[12];
    const float* ln1_g   = (const float*)d_in[13];
    const float* ln1_b   = (const float*)d_in[14];
    const float* ff1_w   = (const float*)d_in[15];
    const float* ff1_b   = (const float*)d_in[16];
    const float* ff2_w   = (const float*)d_in[17];
    const float* ff2_b   = (const float*)d_in[18];
    const float* ln2_g   = (const float*)d_in[19];
    const float* ln2_b   = (const float*)d_in[20];
    const float* lnf_g   = (const float*)d_in[21];
    const float* lnf_b   = (const float*)d_in[22];
    const float* proj_w  = (const float*)d_in[23];
    const float* proj_b  = (const float*)d_in[24];
    float* out = (float*)d_out;

    float* ws = (float*)d_ws;
    const size_t NBT = (size_t)MROWS;
    size_t off = 0;
    float* mean = ws + off; off += 8192;
    float* stdv = ws + off; off += 8192;
    ushort* w_emb3  = (ushort*)(ws + off); off += 393216;    // 512*1536 bf16
    ushort* w_win3  = (ushort*)(ws + off); off += 3145728;   // 4096*1536
    ushort* w_wout3 = (ushort*)(ws + off); off += 1572864;   // 2048*1536
    ushort* w_ff13  = (ushort*)(ws + off); off += 786432;    // 1024*1536
    ushort* w_ff23  = (ushort*)(ws + off); off += 786432;    // 1024*1536
    ushort* tok3 = (ushort*)(ws + off); off += NBT*768;      // 8384*1536 bf16
    ushort* y3   = tok3;                                     // alias (tok3 dead after emb)
    float* h   = ws + off; off += NBT*DD;
    ushort* h3 = (ushort*)(ws + off); off += NBT*768;
    float* xz  = ws + off; off += NBT*2*DD;
    ushort* fft3 = (ushort*)xz;                              // alias (xz dead at ffn time)
    float* xc  = ws + off; off += NBT*DD;
    float* dbl = ws + off; off += NBT*64;
    float* sp  = ws + off; off += NBT*DD;
    float* fbuf = ws + off; off += NBT*DD;
    float* rbuf = ws + off; off += NBT*DD;

    // ---- weight packing (every call; deterministic) ----
    pack3w<<<dim3((512*512+255)/256),  256, 0, stream>>>(emb_w, w_emb3, 512*512);
    pack3w<<<dim3((4096*512+255)/256), 256, 0, stream>>>(m_win, w_win3, 4096*512);
    pack3w<<<dim3((2048*512+255)/256), 256, 0, stream>>>(m_wout, w_wout3, 2048*512);
    pack3w<<<dim3((1024*512+255)/256), 256, 0, stream>>>(ff1_w, w_ff13, 1024*512);
    pack3w<<<dim3((1024*512+255)/256), 256, 0, stream>>>(ff2_w, w_ff23, 1024*512);

    stats_kernel<<<dim3(BB*4), 256, 0, stream>>>(x_enc, mean, stdv);
    tok_kernel<<<dim3(BB*40), 256, 0, stream>>>(x_enc, x_mark, mean, stdv, tok3);

    // h = tok @ emb_w.T + emb_b   (fp32 h + packed h3)
    gemm3<1,0,1,1><<<dim3(66,4), 256, 0, stream>>>(tok3, 1536, w_emb3, 1536,
        emb_b, h, DD, h3, DD, MROWS, 1536);

    for (int l = 0; l < 2; ++l) {
        for (int dir = 0; dir < 2; ++dir) {
            int li = l*2 + dir;
            gemm3<0,0,1,0><<<dim3(66,8), 256, 0, stream>>>(h3, 1536,
                w_win3 + (size_t)li*1024*1536, 1536, nullptr,
                xz, 2*DD, nullptr, 0, MROWS, 1536);
            conv_silu<<<dim3((MROWS*DD)/256), 256, 0, stream>>>(
                xz, m_convw + (size_t)li*DD*2, m_convb + (size_t)li*DD, xc, dir);
            gemm_nt<0><<<dim3(66,1), 256, 0, stream>>>(xc, DD,
                m_wx + (size_t)li*64*DD, nullptr, dbl, 64, MROWS, 64, DD);
            gemm_nt<2><<<dim3(66,4), 256, 0, stream>>>(dbl, 64,
                m_wdt + (size_t)li*DD*RR, m_bdt + (size_t)li*DD, sp, DD,
                MROWS, DD, RR);
            scan2<<<dim3(BB*8), 256, 0, stream>>>(sp, xc, xz, dbl,
                m_alog + (size_t)li*DD*SS, m_dpar + (size_t)li*DD, y3, dir);
            gemm3<0,0,1,0><<<dim3(66,4), 256, 0, stream>>>(y3, 1536,
                w_wout3 + (size_t)li*512*1536, 1536, nullptr,
                (dir == 0) ? fbuf : rbuf, DD, nullptr, 0, MROWS, 1536);
        }
        ln_kernel<<<dim3(MROWS), 64, 0, stream>>>(h, h, fbuf, rbuf,
            ln1_g + l*DD, ln1_b + l*DD, h3);
        gemm3<1,1,0,1><<<dim3(66,4), 256, 0, stream>>>(h3, 1536,
            w_ff13 + (size_t)l*512*1536, 1536, ff1_b + l*DD,
            nullptr, 0, fft3, DD, MROWS, 1536);
        gemm3<1,0,1,0><<<dim3(66,4), 256, 0, stream>>>(fft3, 1536,
            w_ff23 + (size_t)l*512*1536, 1536, ff2_b + l*DD,
            xc, DD, nullptr, 0, MROWS, 1536);
        ln_kernel<<<dim3(MROWS), 64, 0, stream>>>(h, h, xc, nullptr,
            ln2_g + l*DD, ln2_b + l*DD, h3);
    }
    ln_kernel<<<dim3(MROWS), 64, 0, stream>>>(fbuf, h, nullptr, nullptr,
                                              lnf_g, lnf_b, nullptr);
    proj_kernel<<<dim3(BB*32), 128, 0, stream>>>(fbuf, proj_w, proj_b, mean, stdv, out);
}

// Round 5
// 1426.985 us; speedup vs baseline: 2.0944x; 1.9814x over previous
//
#include <hip/hip_runtime.h>
#include <hip/hip_bf16.h>
#include <math.h>
#include <stddef.h>

#define BB 32
#define TT 262
#define DD 512
#define SS 16
#define RR 32
#define SEQ 512
#define NV 256
#define PRED 96
#define MROWS (BB*TT)   // 8384

typedef __attribute__((ext_vector_type(4))) float f32x4;
typedef __attribute__((ext_vector_type(8))) short s16x8;

// ---------------- bf16 helpers ----------------
__device__ inline ushort f2bu(float x) {
    __hip_bfloat16 h = __float2bfloat16(x);
    ushort u; __builtin_memcpy(&u, &h, 2); return u;
}
__device__ inline float bu2f(ushort u) {
    __hip_bfloat16 h; __builtin_memcpy(&h, &u, 2);
    return __bfloat162float(h);
}
// activation 3K pack: [hi | lo | hi]
__device__ inline void pack_act(ushort* base, int col, int Kd, float v) {
    ushort hu = f2bu(v);
    float hf = bu2f(hu);
    ushort lu = f2bu(v - hf);
    base[col] = hu; base[Kd + col] = lu; base[2*Kd + col] = hu;
}

// async global->LDS, 16B per lane (lds dest: wave-uniform base + lane*16)
__device__ inline void gload_lds16(const void* g, void* l) {
    __builtin_amdgcn_global_load_lds(
        (const __attribute__((address_space(1))) void*)g,
        (__attribute__((address_space(3))) void*)l, 16, 0, 0);
}

// ---------------------------------------------------------------------------
// weight 3K pack: [hi | hi | lo], K=512 rows
// ---------------------------------------------------------------------------
__global__ __launch_bounds__(256)
void pack3w(const float* __restrict__ in, ushort* __restrict__ out, int total)
{
    int idx = blockIdx.x * 256 + threadIdx.x;
    if (idx >= total) return;
    int r = idx >> 9, k = idx & 511;
    float x = in[idx];
    ushort hu = f2bu(x);
    float hf = bu2f(hu);
    ushort lu = f2bu(x - hf);
    size_t b = (size_t)r * 1536;
    out[b + k] = hu; out[b + 512 + k] = hu; out[b + 1024 + k] = lu;
}

// ---------------------------------------------------------------------------
// 1) per-(b,n) mean/std over SEQ
// ---------------------------------------------------------------------------
__global__ __launch_bounds__(256)
void stats_kernel(const float* __restrict__ x_enc,
                  float* __restrict__ mean, float* __restrict__ stdv)
{
    int b  = blockIdx.x >> 2;
    int n0 = (blockIdx.x & 3) << 6;
    int lane = threadIdx.x & 63;
    int w    = threadIdx.x >> 6;
    int n = n0 + lane;
    float s = 0.f, s2 = 0.f;
    for (int t = w; t < SEQ; t += 4) {
        float v = x_enc[((size_t)b*SEQ + t)*NV + n];
        s += v; s2 += v*v;
    }
    __shared__ float ls[4][64], ls2[4][64];
    ls[w][lane] = s; ls2[w][lane] = s2;
    __syncthreads();
    if (w == 0) {
        s  = ls[0][lane] + ls[1][lane] + ls[2][lane] + ls[3][lane];
        s2 = ls2[0][lane] + ls2[1][lane] + ls2[2][lane] + ls2[3][lane];
        float mu  = s * (1.f/SEQ);
        float var = s2 * (1.f/SEQ) - mu*mu;
        mean[b*NV + n] = mu;
        stdv[b*NV + n] = sqrtf(var + 1e-5f);
    }
}

// ---------------------------------------------------------------------------
// 2) tok3: normalized transpose packed [hi|lo|hi] over K=512
// ---------------------------------------------------------------------------
__global__ __launch_bounds__(256)
void tok_kernel(const float* __restrict__ x_enc, const float* __restrict__ x_mark,
                const float* __restrict__ mean, const float* __restrict__ stdv,
                ushort* __restrict__ tok3)
{
    int b  = blockIdx.x / 40;
    int r  = blockIdx.x % 40;
    int tt = r / 5;
    int vt = r % 5;
    int t0 = tt << 6, v0 = vt << 6;
    __shared__ float tile[64][65];
    int lv = threadIdx.x & 63;
    for (int i = threadIdx.x >> 6; i < 64; i += 4) {
        int t = t0 + i, v = v0 + lv;
        float val = 0.f;
        if (v < NV) {
            val = (x_enc[((size_t)b*SEQ + t)*NV + v] - mean[b*NV + v]) / stdv[b*NV + v];
        } else if (v < TT) {
            val = x_mark[((size_t)b*SEQ + t)*6 + (v - NV)];
        }
        tile[i][lv] = val;
    }
    __syncthreads();
    for (int i = threadIdx.x >> 6; i < 64; i += 4) {
        int v = v0 + i;
        if (v < TT) {
            size_t row = (size_t)b*TT + v;
            pack_act(tok3 + row*1536, t0 + lv, 512, tile[lv][i]);
        }
    }
}

// ---------------------------------------------------------------------------
// 3) bf16 MFMA GEMM over packed 3K operands (NT; K3 multiple of 64).
//    128x128 tile, BK=64, 256 thr (4 waves 2x2, each 64x64 out).
//    global_load_lds(16B) staging into linear double-buffered LDS;
//    source-slot XOR swizzle + matching ds_read swizzle (conflict-free).
// ---------------------------------------------------------------------------
template<int HAS_BIAS, int RELU, int WF32, int W3>
__global__ __launch_bounds__(256)
void gemm3(const ushort* __restrict__ A3, int lda3,
           const ushort* __restrict__ W3p, int ldw3,
           const float* __restrict__ bias,
           float* __restrict__ C, int ldc,
           ushort* __restrict__ C3, int N_out,
           int M, int K3)
{
    __shared__ ushort lds[2][2][128*64];   // [buf][A=0/W=1][row*64+e] : 64 KB
    const int tid  = threadIdx.x;
    const int lane = tid & 63;
    const int wid  = tid >> 6;
    const int wr = wid >> 1, wc = wid & 1;
    const int m0 = blockIdx.x * 128;
    const int n0 = blockIdx.y * 128;

    const int l8 = lane >> 3;          // row-in-chunk 0..7
    const int sl = lane & 7;           // dest slot 0..7
    const int ssl = sl ^ l8;           // swizzled SOURCE slot

    // global rows for the 4 (A,W) chunks this wave stages (chunk = 8 rows)
    int arow[4], wrow[4];
    #pragma unroll
    for (int q = 0; q < 4; ++q) {
        int r = (wid*4 + q)*8 + l8;
        int ar = m0 + r; if (ar > M-1) ar = M-1;
        arow[q] = ar;
        wrow[q] = n0 + r;
    }

    f32x4 acc[4][4];
    #pragma unroll
    for (int i = 0; i < 4; ++i)
        #pragma unroll
        for (int j = 0; j < 4; ++j) acc[i][j] = (f32x4){0.f,0.f,0.f,0.f};

    const int nk = K3 >> 6;
    const int rl = lane & 15;
    const int kq = lane >> 4;

    auto stage = [&](int buf_, int kt_) {
        #pragma unroll
        for (int q = 0; q < 4; ++q) {
            int c = wid*4 + q;
            gload_lds16(A3 + (size_t)arow[q]*lda3 + kt_*64 + ssl*8,
                        (void*)&lds[buf_][0][c*512]);
            gload_lds16(W3p + (size_t)wrow[q]*ldw3 + kt_*64 + ssl*8,
                        (void*)&lds[buf_][1][c*512]);
        }
    };

    stage(0, 0);
    __syncthreads();

    for (int kt = 0; kt < nk; ++kt) {
        int cur = kt & 1;
        if (kt + 1 < nk) stage(cur ^ 1, kt + 1);
        #pragma unroll
        for (int kk = 0; kk < 2; ++kk) {
            s16x8 av[4], wv[4];
            #pragma unroll
            for (int mi = 0; mi < 4; ++mi) {
                int row = wr*64 + mi*16 + rl;
                int ck = (kk*4 + kq) ^ (row & 7);
                av[mi] = *(const s16x8*)&lds[cur][0][row*64 + (ck<<3)];
            }
            #pragma unroll
            for (int ni = 0; ni < 4; ++ni) {
                int row = wc*64 + ni*16 + rl;
                int ck = (kk*4 + kq) ^ (row & 7);
                wv[ni] = *(const s16x8*)&lds[cur][1][row*64 + (ck<<3)];
            }
            #pragma unroll
            for (int mi = 0; mi < 4; ++mi)
                #pragma unroll
                for (int ni = 0; ni < 4; ++ni)
                    acc[mi][ni] = __builtin_amdgcn_mfma_f32_16x16x32_bf16(
                        av[mi], wv[ni], acc[mi][ni], 0, 0, 0);
        }
        __syncthreads();
    }

    // epilogue: D col = lane&15 (n), row = kq*4 + j (m)
    #pragma unroll
    for (int ni = 0; ni < 4; ++ni) {
        int n = n0 + wc*64 + ni*16 + rl;
        float bv = HAS_BIAS ? bias[n] : 0.f;
        #pragma unroll
        for (int mi = 0; mi < 4; ++mi) {
            #pragma unroll
            for (int j = 0; j < 4; ++j) {
                int m = m0 + wr*64 + mi*16 + kq*4 + j;
                if (m >= M) continue;
                float v = acc[mi][ni][j];
                if (HAS_BIAS) v += bv;
                if (RELU) v = fmaxf(v, 0.f);
                if (WF32) C[(size_t)m*ldc + n] = v;
                if (W3)   pack_act(C3 + (size_t)m*(3*N_out), n, N_out, v);
            }
        }
    }
}

// ---------------------------------------------------------------------------
// 4) fp32 GEMM (kept for wx / wdt). ACT: 0 none, 2 softplus.
// ---------------------------------------------------------------------------
template<int ACT>
__global__ __launch_bounds__(256)
void gemm_nt(const float* __restrict__ A, int lda,
             const float* __restrict__ W,
             const float* __restrict__ bias,
             float* __restrict__ C, int ldc,
             int M, int N, int K)
{
    __shared__ float Asl[8][128];
    __shared__ float Bsl[8][128];
    int m0 = blockIdx.x * 128;
    int n0 = blockIdx.y * 128;
    int tid = threadIdx.x;
    int lrow = tid >> 1, lseg = tid & 1;
    int tx = tid & 15, ty = tid >> 4;

    int arow = m0 + lrow; if (arow >= M) arow = M - 1;
    int brow = n0 + lrow; if (brow >= N) brow = N - 1;
    const float* Ag = A + (size_t)arow*lda + lseg*4;
    const float* Wg = W + (size_t)brow*K   + lseg*4;

    float acc[8][8];
    #pragma unroll
    for (int i = 0; i < 8; ++i)
        #pragma unroll
        for (int j = 0; j < 8; ++j) acc[i][j] = 0.f;

    float4 aR = *(const float4*)Ag;
    float4 bR = *(const float4*)Wg;

    int nk = K >> 3;
    for (int kt = 0; kt < nk; ++kt) {
        Asl[lseg*4+0][lrow] = aR.x; Asl[lseg*4+1][lrow] = aR.y;
        Asl[lseg*4+2][lrow] = aR.z; Asl[lseg*4+3][lrow] = aR.w;
        Bsl[lseg*4+0][lrow] = bR.x; Bsl[lseg*4+1][lrow] = bR.y;
        Bsl[lseg*4+2][lrow] = bR.z; Bsl[lseg*4+3][lrow] = bR.w;
        __syncthreads();
        if (kt + 1 < nk) {
            aR = *(const float4*)(Ag + (kt+1)*8);
            bR = *(const float4*)(Wg + (kt+1)*8);
        }
        #pragma unroll
        for (int kk = 0; kk < 8; ++kk) {
            float af[8], bf[8];
            *(float4*)(af)   = *(const float4*)&Asl[kk][ty*4];
            *(float4*)(af+4) = *(const float4*)&Asl[kk][64 + ty*4];
            *(float4*)(bf)   = *(const float4*)&Bsl[kk][tx*4];
            *(float4*)(bf+4) = *(const float4*)&Bsl[kk][64 + tx*4];
            #pragma unroll
            for (int i = 0; i < 8; ++i)
                #pragma unroll
                for (int j = 0; j < 8; ++j)
                    acc[i][j] = fmaf(af[i], bf[j], acc[i][j]);
        }
        __syncthreads();
    }

    #pragma unroll
    for (int ih = 0; ih < 2; ++ih) {
        #pragma unroll
        for (int i = 0; i < 4; ++i) {
            int m = m0 + ih*64 + ty*4 + i;
            if (m >= M) continue;
            #pragma unroll
            for (int jh = 0; jh < 2; ++jh) {
                int n = n0 + jh*64 + tx*4;
                if (n >= N) continue;
                #pragma unroll
                for (int jj = 0; jj < 4; ++jj) {
                    float v = acc[ih*4+i][jh*4+jj];
                    if (bias) v += bias[n+jj];
                    if (ACT == 2) v = fmaxf(v, 0.f) + log1pf(__expf(-fabsf(v)));
                    C[(size_t)m*ldc + n + jj] = v;
                }
            }
        }
    }
}

// ---------------------------------------------------------------------------
// 5) conv + SiLU, and in-place silu on z-half of xz
// ---------------------------------------------------------------------------
__global__ __launch_bounds__(256)
void conv_silu(float* __restrict__ xz, const float* __restrict__ cw,
               const float* __restrict__ cb, float* __restrict__ xc, int rev)
{
    int idx = blockIdx.x * 256 + threadIdx.x;
    int d  = idx & (DD-1);
    int bt = idx >> 9;
    int t  = bt % TT;
    float cur = xz[(size_t)bt*2*DD + d];
    int tn = rev ? t + 1 : t - 1;
    float prev = 0.f;
    if (tn >= 0 && tn < TT)
        prev = xz[((size_t)bt + (rev ? 1 : -1))*2*DD + d];
    float v = prev*cw[d*2] + cur*cw[d*2+1] + cb[d];
    xc[idx] = v / (1.f + __expf(-v));
    float z = xz[(size_t)bt*2*DD + DD + d];
    xz[(size_t)bt*2*DD + DD + d] = z / (1.f + __expf(-z));
}

// ---------------------------------------------------------------------------
// 6) Scan V2: LDS-chunked. block=(b, 64 d), 256 thr = 64 d x 4 s-groups.
// ---------------------------------------------------------------------------
#define CH 32
__global__ __launch_bounds__(256)
void scan2(const float* __restrict__ sp_g, const float* __restrict__ xc_g,
           const float* __restrict__ xz_g, const float* __restrict__ dbl_g,
           const float* __restrict__ alog, const float* __restrict__ dparam,
           ushort* __restrict__ y3, int rev)
{
    int b  = blockIdx.x >> 3;
    int d0 = (blockIdx.x & 7) << 6;
    int tid = threadIdx.x;
    int sg = tid & 3;
    int dl = tid >> 2;
    int d  = d0 + dl;

    __shared__ float t_sp[CH][68], t_xc[CH][68], t_zs[CH][68], t_bc[CH][36];

    float Ac[4];
    #pragma unroll
    for (int j = 0; j < 4; ++j)
        Ac[j] = -__expf(alog[d*SS + sg*4 + j]);
    float dp = dparam[d];
    float h0=0.f, h1=0.f, h2=0.f, h3=0.f;
    size_t bbase = (size_t)b*TT;

    int r_a = tid >> 4, c_a = (tid & 15) << 2;
    int r_a2 = (tid + 256) >> 4, c_a2 = ((tid + 256) & 15) << 2;
    int r_b = tid >> 3, c_b = (tid & 7) << 2;

#define GROW(tg_) (rev ? (TT-1-(tg_)) : (tg_))
#define LOADCH(c_, s0,s1, x0,x1, z0,z1, bc0) { \
        int tgA = (c_)*CH + r_a;  if (tgA > TT-1) tgA = TT-1; \
        int tgB = (c_)*CH + r_a2; if (tgB > TT-1) tgB = TT-1; \
        int tgC = (c_)*CH + r_b;  if (tgC > TT-1) tgC = TT-1; \
        size_t pA = bbase + GROW(tgA), pB = bbase + GROW(tgB), pC = bbase + GROW(tgC); \
        s0 = *(const float4*)(sp_g + pA*DD + d0 + c_a); \
        s1 = *(const float4*)(sp_g + pB*DD + d0 + c_a2); \
        x0 = *(const float4*)(xc_g + pA*DD + d0 + c_a); \
        x1 = *(const float4*)(xc_g + pB*DD + d0 + c_a2); \
        z0 = *(const float4*)(xz_g + pA*2*DD + DD + d0 + c_a); \
        z1 = *(const float4*)(xz_g + pB*2*DD + DD + d0 + c_a2); \
        bc0 = *(const float4*)(dbl_g + pC*64 + 32 + c_b); }

    float4 s0,s1,x0,x1,z0,z1,bc0;
    LOADCH(0, s0,s1,x0,x1,z0,z1,bc0);

    const int nch = (TT + CH - 1) / CH;
    for (int c = 0; c < nch; ++c) {
        __syncthreads();
        *(float4*)&t_sp[r_a ][c_a ] = s0;
        *(float4*)&t_sp[r_a2][c_a2] = s1;
        *(float4*)&t_xc[r_a ][c_a ] = x0;
        *(float4*)&t_xc[r_a2][c_a2] = x1;
        *(float4*)&t_zs[r_a ][c_a ] = z0;
        *(float4*)&t_zs[r_a2][c_a2] = z1;
        *(float4*)&t_bc[r_b ][c_b ] = bc0;
        if (c + 1 < nch)
            LOADCH(c+1, s0,s1,x0,x1,z0,z1,bc0);
        __syncthreads();

        int steps = TT - c*CH; if (steps > CH) steps = CH;
        for (int i = 0; i < steps; ++i) {
            float spv = t_sp[i][dl];
            float xcv = t_xc[i][dl];
            float4 Bv = *(const float4*)&t_bc[i][sg*4];
            float4 Cv = *(const float4*)&t_bc[i][16 + sg*4];
            float dtxc = spv * xcv;
            h0 = fmaf(__expf(spv*Ac[0]), h0, dtxc*Bv.x);
            h1 = fmaf(__expf(spv*Ac[1]), h1, dtxc*Bv.y);
            h2 = fmaf(__expf(spv*Ac[2]), h2, dtxc*Bv.z);
            h3 = fmaf(__expf(spv*Ac[3]), h3, dtxc*Bv.w);
            float dot = h0*Cv.x + h1*Cv.y + h2*Cv.z + h3*Cv.w;
            dot += __shfl_xor(dot, 1);
            dot += __shfl_xor(dot, 2);
            if (sg == 0) {
                int t = GROW(c*CH + i);
                float yv = (dot + dp*xcv) * t_zs[i][dl];
                pack_act(y3 + (bbase + t)*1536, d, 512, yv);
            }
        }
    }
#undef LOADCH
#undef GROW
}

// ---------------------------------------------------------------------------
// 7) LayerNorm (up to 3 summed inputs), optional 3K-pack output
// ---------------------------------------------------------------------------
__global__ __launch_bounds__(64)
void ln_kernel(float* __restrict__ dst, const float* __restrict__ a,
               const float* __restrict__ b, const float* __restrict__ c,
               const float* __restrict__ g, const float* __restrict__ beta,
               ushort* __restrict__ out3)
{
    int row = blockIdx.x;
    int lane = threadIdx.x;
    size_t base = (size_t)row * DD;
    float x[8];
    #pragma unroll
    for (int j = 0; j < 2; ++j) {
        int e4 = j*64 + lane;
        float4 v = *(const float4*)(a + base + (size_t)e4*4);
        if (b) { float4 t = *(const float4*)(b + base + (size_t)e4*4); v.x+=t.x; v.y+=t.y; v.z+=t.z; v.w+=t.w; }
        if (c) { float4 t = *(const float4*)(c + base + (size_t)e4*4); v.x+=t.x; v.y+=t.y; v.z+=t.z; v.w+=t.w; }
        x[j*4+0]=v.x; x[j*4+1]=v.y; x[j*4+2]=v.z; x[j*4+3]=v.w;
    }
    float s = 0.f;
    #pragma unroll
    for (int i = 0; i < 8; ++i) s += x[i];
    #pragma unroll
    for (int m = 1; m < 64; m <<= 1) s += __shfl_xor(s, m);
    float mu = s * (1.f/DD);
    float vs = 0.f;
    #pragma unroll
    for (int i = 0; i < 8; ++i) { float dd = x[i]-mu; vs += dd*dd; }
    #pragma unroll
    for (int m = 1; m < 64; m <<= 1) vs += __shfl_xor(vs, m);
    float r = rsqrtf(vs*(1.f/DD) + 1e-5f);
    #pragma unroll
    for (int j = 0; j < 2; ++j) {
        int e4 = j*64 + lane;
        float4 gv = *(const float4*)(g    + (size_t)e4*4);
        float4 bv = *(const float4*)(beta + (size_t)e4*4);
        float4 o;
        o.x = (x[j*4+0]-mu)*r*gv.x + bv.x;
        o.y = (x[j*4+1]-mu)*r*gv.y + bv.y;
        o.z = (x[j*4+2]-mu)*r*gv.z + bv.z;
        o.w = (x[j*4+3]-mu)*r*gv.w + bv.w;
        *(float4*)(dst + base + (size_t)e4*4) = o;
        if (out3) {
            ushort* ob = out3 + (size_t)row*1536;
            pack_act(ob, e4*4+0, 512, o.x);
            pack_act(ob, e4*4+1, 512, o.y);
            pack_act(ob, e4*4+2, 512, o.z);
            pack_act(ob, e4*4+3, 512, o.w);
        }
    }
}

// ---------------------------------------------------------------------------
// 8) projection + transpose + de-norm
// ---------------------------------------------------------------------------
__global__ __launch_bounds__(128)
void proj_kernel(const float* __restrict__ hf, const float* __restrict__ pw,
                 const float* __restrict__ pb, const float* __restrict__ mean,
                 const float* __restrict__ stdv, float* __restrict__ out)
{
    int b  = blockIdx.x >> 5;
    int n0 = (blockIdx.x & 31) << 3;
    __shared__ float rows[8][DD];
    for (int i = threadIdx.x; i < 8*128; i += 128) {
        int rj = i >> 7, c4 = i & 127;
        ((float4*)rows[rj])[c4] =
            *(const float4*)(hf + ((size_t)b*TT + n0 + rj)*DD + (size_t)c4*4);
    }
    __syncthreads();
    int p = threadIdx.x;
    if (p < PRED) {
        float acc[8];
        #pragma unroll
        for (int j = 0; j < 8; ++j) acc[j] = 0.f;
        for (int k4 = 0; k4 < 128; ++k4) {
            float4 w = *(const float4*)(pw + (size_t)p*DD + (size_t)k4*4);
            #pragma unroll
            for (int j = 0; j < 8; ++j) {
                float4 rv = ((const float4*)rows[j])[k4];
                acc[j] += w.x*rv.x + w.y*rv.y + w.z*rv.z + w.w*rv.w;
            }
        }
        float bias = pb[p];
        #pragma unroll
        for (int j = 0; j < 8; ++j) {
            int n = n0 + j;
            out[((size_t)b*PRED + p)*NV + n] =
                (acc[j] + bias)*stdv[b*NV + n] + mean[b*NV + n];
        }
    }
}

// ---------------------------------------------------------------------------
extern "C" void kernel_launch(void* const* d_in, const int* in_sizes, int n_in,
                              void* d_out, int out_size, void* d_ws, size_t ws_size,
                              hipStream_t stream)
{
    (void)in_sizes; (void)n_in; (void)out_size; (void)ws_size;
    const float* x_enc   = (const float*)d_in[0];
    const float* x_mark  = (const float*)d_in[1];
    const float* emb_w   = (const float*)d_in[2];
    const float* emb_b   = (const float*)d_in[3];
    const float* m_win   = (const float*)d_in[4];
    const float* m_convw = (const float*)d_in[5];
    const float* m_convb = (const float*)d_in[6];
    const float* m_wx    = (const float*)d_in[7];
    const float* m_wdt   = (const float*)d_in[8];
    const float* m_bdt   = (const float*)d_in[9];
    const float* m_alog  = (const float*)d_in[10];
    const float* m_dpar  = (const float*)d_in[11];
    const float* m_wout  = (const float*)d_in[12];
    const float* ln1_g   = (const float*)d_in[13];
    const float* ln1_b   = (const float*)d_in[14];
    const float* ff1_w   = (const float*)d_in[15];
    const float* ff1_b   = (const float*)d_in[16];
    const float* ff2_w   = (const float*)d_in[17];
    const float* ff2_b   = (const float*)d_in[18];
    const float* ln2_g   = (const float*)d_in[19];
    const float* ln2_b   = (const float*)d_in[20];
    const float* lnf_g   = (const float*)d_in[21];
    const float* lnf_b   = (const float*)d_in[22];
    const float* proj_w  = (const float*)d_in[23];
    const float* proj_b  = (const float*)d_in[24];
    float* out = (float*)d_out;

    float* ws = (float*)d_ws;
    const size_t NBT = (size_t)MROWS;
    size_t off = 0;
    float* mean = ws + off; off += 8192;
    float* stdv = ws + off; off += 8192;
    ushort* w_emb3  = (ushort*)(ws + off); off += 393216;    // 512*1536 bf16
    ushort* w_win3  = (ushort*)(ws + off); off += 3145728;   // 4096*1536
    ushort* w_wout3 = (ushort*)(ws + off); off += 1572864;   // 2048*1536
    ushort* w_ff13  = (ushort*)(ws + off); off += 786432;    // 1024*1536
    ushort* w_ff23  = (ushort*)(ws + off); off += 786432;    // 1024*1536
    ushort* tok3 = (ushort*)(ws + off); off += NBT*768;      // 8384*1536 bf16
    ushort* y3   = tok3;                                     // alias (tok3 dead after emb)
    float* h   = ws + off; off += NBT*DD;
    ushort* h3 = (ushort*)(ws + off); off += NBT*768;
    float* xz  = ws + off; off += NBT*2*DD;
    ushort* fft3 = (ushort*)xz;                              // alias (xz dead at ffn time)
    float* xc  = ws + off; off += NBT*DD;
    float* dbl = ws + off; off += NBT*64;
    float* sp  = ws + off; off += NBT*DD;
    float* fbuf = ws + off; off += NBT*DD;
    float* rbuf = ws + off; off += NBT*DD;

    // ---- weight packing (every call; deterministic) ----
    pack3w<<<dim3((512*512+255)/256),  256, 0, stream>>>(emb_w, w_emb3, 512*512);
    pack3w<<<dim3((4096*512+255)/256), 256, 0, stream>>>(m_win, w_win3, 4096*512);
    pack3w<<<dim3((2048*512+255)/256), 256, 0, stream>>>(m_wout, w_wout3, 2048*512);
    pack3w<<<dim3((1024*512+255)/256), 256, 0, stream>>>(ff1_w, w_ff13, 1024*512);
    pack3w<<<dim3((1024*512+255)/256), 256, 0, stream>>>(ff2_w, w_ff23, 1024*512);

    stats_kernel<<<dim3(BB*4), 256, 0, stream>>>(x_enc, mean, stdv);
    tok_kernel<<<dim3(BB*40), 256, 0, stream>>>(x_enc, x_mark, mean, stdv, tok3);

    // h = tok @ emb_w.T + emb_b   (fp32 h + packed h3)
    gemm3<1,0,1,1><<<dim3(66,4), 256, 0, stream>>>(tok3, 1536, w_emb3, 1536,
        emb_b, h, DD, h3, DD, MROWS, 1536);

    for (int l = 0; l < 2; ++l) {
        for (int dir = 0; dir < 2; ++dir) {
            int li = l*2 + dir;
            gemm3<0,0,1,0><<<dim3(66,8), 256, 0, stream>>>(h3, 1536,
                w_win3 + (size_t)li*1024*1536, 1536, nullptr,
                xz, 2*DD, nullptr, 0, MROWS, 1536);
            conv_silu<<<dim3((MROWS*DD)/256), 256, 0, stream>>>(
                xz, m_convw + (size_t)li*DD*2, m_convb + (size_t)li*DD, xc, dir);
            gemm_nt<0><<<dim3(66,1), 256, 0, stream>>>(xc, DD,
                m_wx + (size_t)li*64*DD, nullptr, dbl, 64, MROWS, 64, DD);
            gemm_nt<2><<<dim3(66,4), 256, 0, stream>>>(dbl, 64,
                m_wdt + (size_t)li*DD*RR, m_bdt + (size_t)li*DD, sp, DD,
                MROWS, DD, RR);
            scan2<<<dim3(BB*8), 256, 0, stream>>>(sp, xc, xz, dbl,
                m_alog + (size_t)li*DD*SS, m_dpar + (size_t)li*DD, y3, dir);
            gemm3<0,0,1,0><<<dim3(66,4), 256, 0, stream>>>(y3, 1536,
                w_wout3 + (size_t)li*512*1536, 1536, nullptr,
                (dir == 0) ? fbuf : rbuf, DD, nullptr, 0, MROWS, 1536);
        }
        ln_kernel<<<dim3(MROWS), 64, 0, stream>>>(h, h, fbuf, rbuf,
            ln1_g + l*DD, ln1_b + l*DD, h3);
        gemm3<1,1,0,1><<<dim3(66,4), 256, 0, stream>>>(h3, 1536,
            w_ff13 + (size_t)l*512*1536, 1536, ff1_b + l*DD,
            nullptr, 0, fft3, DD, MROWS, 1536);
        gemm3<1,0,1,0><<<dim3(66,4), 256, 0, stream>>>(fft3, 1536,
            w_ff23 + (size_t)l*512*1536, 1536, ff2_b + l*DD,
            xc, DD, nullptr, 0, MROWS, 1536);
        ln_kernel<<<dim3(MROWS), 64, 0, stream>>>(h, h, xc, nullptr,
            ln2_g + l*DD, ln2_b + l*DD, h3);
    }
    ln_kernel<<<dim3(MROWS), 64, 0, stream>>>(fbuf, h, nullptr, nullptr,
                                              lnf_g, lnf_b, nullptr);
    proj_kernel<<<dim3(BB*32), 128, 0, stream>>>(fbuf, proj_w, proj_b, mean, stdv, out);
}

// Round 6
// 1278.498 us; speedup vs baseline: 2.3377x; 1.1161x over previous
//
#include <hip/hip_runtime.h>
#include <hip/hip_bf16.h>
#include <math.h>
#include <stddef.h>

#define BB 32
#define TT 262
#define DD 512
#define SS 16
#define RR 32
#define SEQ 512
#define NV 256
#define PRED 96
#define MROWS (BB*TT)   // 8384

typedef __attribute__((ext_vector_type(4))) float f32x4;
typedef __attribute__((ext_vector_type(8))) short s16x8;

// ---------------- bf16 helpers ----------------
__device__ inline ushort f2bu(float x) {
    __hip_bfloat16 h = __float2bfloat16(x);
    ushort u; __builtin_memcpy(&u, &h, 2); return u;
}
__device__ inline float bu2f(ushort u) {
    __hip_bfloat16 h; __builtin_memcpy(&h, &u, 2);
    return __bfloat162float(h);
}
// activation 3K pack: [hi | lo | hi]
__device__ inline void pack_act(ushort* base, int col, int Kd, float v) {
    ushort hu = f2bu(v);
    float hf = bu2f(hu);
    ushort lu = f2bu(v - hf);
    base[col] = hu; base[Kd + col] = lu; base[2*Kd + col] = hu;
}

// async global->LDS, 16B per lane (lds dest: wave-uniform base + lane*16)
__device__ inline void gload_lds16(const void* g, void* l) {
    __builtin_amdgcn_global_load_lds(
        (const __attribute__((address_space(1))) void*)g,
        (__attribute__((address_space(3))) void*)l, 16, 0, 0);
}

// ---------------------------------------------------------------------------
// weight 3K pack: [hi | hi | lo], K=512 rows
// ---------------------------------------------------------------------------
__global__ __launch_bounds__(256)
void pack3w(const float* __restrict__ in, ushort* __restrict__ out, int total)
{
    int idx = blockIdx.x * 256 + threadIdx.x;
    if (idx >= total) return;
    int r = idx >> 9, k = idx & 511;
    float x = in[idx];
    ushort hu = f2bu(x);
    float hf = bu2f(hu);
    ushort lu = f2bu(x - hf);
    size_t b = (size_t)r * 1536;
    out[b + k] = hu; out[b + 512 + k] = hu; out[b + 1024 + k] = lu;
}

// ---------------------------------------------------------------------------
// 0) combined scan-projection weight:
//    rows 0..511:  W'[n,k] = sum_{r<32} wdt[n,r]*wx[r,k]   (dt path)
//    rows 512..543: wx[32+s, k]                             (B,C path)
//    packed [hi|hi|lo].  grid (544, 4 li), 256 thr.
// ---------------------------------------------------------------------------
__global__ __launch_bounds__(256)
void mkcomb(const float* __restrict__ wx, const float* __restrict__ wdt,
            ushort* __restrict__ comb3)
{
    int n  = blockIdx.x;
    int li = blockIdx.y;
    const float* wxl = wx + (size_t)li*64*512;
    ushort* outb = comb3 + ((size_t)li*544 + n)*1536;
    if (n < 512) {
        __shared__ float wr[32];
        if (threadIdx.x < 32)
            wr[threadIdx.x] = wdt[(size_t)li*512*32 + (size_t)n*32 + threadIdx.x];
        __syncthreads();
        for (int kk = threadIdx.x; kk < 512; kk += 256) {
            float acc = 0.f;
            #pragma unroll
            for (int r = 0; r < 32; ++r)
                acc = fmaf(wr[r], wxl[r*512 + kk], acc);
            ushort hu = f2bu(acc); float hf = bu2f(hu);
            ushort lu = f2bu(acc - hf);
            outb[kk] = hu; outb[512+kk] = hu; outb[1024+kk] = lu;
        }
    } else {
        int s = n - 512;
        for (int kk = threadIdx.x; kk < 512; kk += 256) {
            float v = wxl[(32+s)*512 + kk];
            ushort hu = f2bu(v); float hf = bu2f(hu);
            ushort lu = f2bu(v - hf);
            outb[kk] = hu; outb[512+kk] = hu; outb[1024+kk] = lu;
        }
    }
}

// ---------------------------------------------------------------------------
// 1) per-(b,n) mean/std over SEQ
// ---------------------------------------------------------------------------
__global__ __launch_bounds__(256)
void stats_kernel(const float* __restrict__ x_enc,
                  float* __restrict__ mean, float* __restrict__ stdv)
{
    int b  = blockIdx.x >> 2;
    int n0 = (blockIdx.x & 3) << 6;
    int lane = threadIdx.x & 63;
    int w    = threadIdx.x >> 6;
    int n = n0 + lane;
    float s = 0.f, s2 = 0.f;
    for (int t = w; t < SEQ; t += 4) {
        float v = x_enc[((size_t)b*SEQ + t)*NV + n];
        s += v; s2 += v*v;
    }
    __shared__ float ls[4][64], ls2[4][64];
    ls[w][lane] = s; ls2[w][lane] = s2;
    __syncthreads();
    if (w == 0) {
        s  = ls[0][lane] + ls[1][lane] + ls[2][lane] + ls[3][lane];
        s2 = ls2[0][lane] + ls2[1][lane] + ls2[2][lane] + ls2[3][lane];
        float mu  = s * (1.f/SEQ);
        float var = s2 * (1.f/SEQ) - mu*mu;
        mean[b*NV + n] = mu;
        stdv[b*NV + n] = sqrtf(var + 1e-5f);
    }
}

// ---------------------------------------------------------------------------
// 2) tok3: normalized transpose packed [hi|lo|hi] over K=512
// ---------------------------------------------------------------------------
__global__ __launch_bounds__(256)
void tok_kernel(const float* __restrict__ x_enc, const float* __restrict__ x_mark,
                const float* __restrict__ mean, const float* __restrict__ stdv,
                ushort* __restrict__ tok3)
{
    int b  = blockIdx.x / 40;
    int r  = blockIdx.x % 40;
    int tt = r / 5;
    int vt = r % 5;
    int t0 = tt << 6, v0 = vt << 6;
    __shared__ float tile[64][65];
    int lv = threadIdx.x & 63;
    for (int i = threadIdx.x >> 6; i < 64; i += 4) {
        int t = t0 + i, v = v0 + lv;
        float val = 0.f;
        if (v < NV) {
            val = (x_enc[((size_t)b*SEQ + t)*NV + v] - mean[b*NV + v]) / stdv[b*NV + v];
        } else if (v < TT) {
            val = x_mark[((size_t)b*SEQ + t)*6 + (v - NV)];
        }
        tile[i][lv] = val;
    }
    __syncthreads();
    for (int i = threadIdx.x >> 6; i < 64; i += 4) {
        int v = v0 + i;
        if (v < TT) {
            size_t row = (size_t)b*TT + v;
            pack_act(tok3 + row*1536, t0 + lv, 512, tile[lv][i]);
        }
    }
}

// ---------------------------------------------------------------------------
// 3) bf16 MFMA GEMM over packed 3K operands (NT; K3 multiple of 64).
//    128x128 tile, BK=64, 256 thr; global_load_lds dbuf; swizzled.
//    SCANEP: cols 0..511 -> softplus(v + bias[n]) into C (ldc=512);
//            cols 512..543 -> bcbuf[m*32 + (n-512)]
// ---------------------------------------------------------------------------
template<int HAS_BIAS, int RELU, int WF32, int W3, int SCANEP>
__global__ __launch_bounds__(256)
void gemm3(const ushort* __restrict__ A3, int lda3,
           const ushort* __restrict__ W3p, int ldw3,
           const float* __restrict__ bias,
           float* __restrict__ C, int ldc,
           ushort* __restrict__ C3, int N_out,
           float* __restrict__ bcbuf,
           int M, int Nn, int K3)
{
    __shared__ ushort lds[2][2][128*64];   // [buf][A=0/W=1] : 64 KB
    const int tid  = threadIdx.x;
    const int lane = tid & 63;
    const int wid  = tid >> 6;
    const int wr = wid >> 1, wc = wid & 1;
    const int m0 = blockIdx.x * 128;
    const int n0 = blockIdx.y * 128;

    const int l8 = lane >> 3;          // row-in-chunk 0..7
    const int sl = lane & 7;           // dest slot 0..7
    const int ssl = sl ^ l8;           // swizzled SOURCE slot

    int arow[4], wrow[4];
    #pragma unroll
    for (int q = 0; q < 4; ++q) {
        int r = (wid*4 + q)*8 + l8;
        int ar = m0 + r; if (ar > M-1) ar = M-1;
        arow[q] = ar;
        int wrr = n0 + r; if (wrr > Nn-1) wrr = Nn-1;
        wrow[q] = wrr;
    }

    f32x4 acc[4][4];
    #pragma unroll
    for (int i = 0; i < 4; ++i)
        #pragma unroll
        for (int j = 0; j < 4; ++j) acc[i][j] = (f32x4){0.f,0.f,0.f,0.f};

    const int nk = K3 >> 6;
    const int rl = lane & 15;
    const int kq = lane >> 4;

    auto stage = [&](int buf_, int kt_) {
        #pragma unroll
        for (int q = 0; q < 4; ++q) {
            int c = wid*4 + q;
            gload_lds16(A3 + (size_t)arow[q]*lda3 + kt_*64 + ssl*8,
                        (void*)&lds[buf_][0][c*512]);
            gload_lds16(W3p + (size_t)wrow[q]*ldw3 + kt_*64 + ssl*8,
                        (void*)&lds[buf_][1][c*512]);
        }
    };

    stage(0, 0);
    __syncthreads();

    for (int kt = 0; kt < nk; ++kt) {
        int cur = kt & 1;
        if (kt + 1 < nk) stage(cur ^ 1, kt + 1);
        #pragma unroll
        for (int kk = 0; kk < 2; ++kk) {
            s16x8 av[4], wv[4];
            #pragma unroll
            for (int mi = 0; mi < 4; ++mi) {
                int row = wr*64 + mi*16 + rl;
                int ck = (kk*4 + kq) ^ (row & 7);
                av[mi] = *(const s16x8*)&lds[cur][0][row*64 + (ck<<3)];
            }
            #pragma unroll
            for (int ni = 0; ni < 4; ++ni) {
                int row = wc*64 + ni*16 + rl;
                int ck = (kk*4 + kq) ^ (row & 7);
                wv[ni] = *(const s16x8*)&lds[cur][1][row*64 + (ck<<3)];
            }
            #pragma unroll
            for (int mi = 0; mi < 4; ++mi)
                #pragma unroll
                for (int ni = 0; ni < 4; ++ni)
                    acc[mi][ni] = __builtin_amdgcn_mfma_f32_16x16x32_bf16(
                        av[mi], wv[ni], acc[mi][ni], 0, 0, 0);
        }
        __syncthreads();
    }

    // epilogue: D col(n) = lane&15, row(m) = kq*4 + j
    #pragma unroll
    for (int ni = 0; ni < 4; ++ni) {
        int n = n0 + wc*64 + ni*16 + rl;
        if (n >= Nn) continue;
        float bv = (HAS_BIAS && !SCANEP) ? bias[n] : 0.f;
        #pragma unroll
        for (int mi = 0; mi < 4; ++mi) {
            #pragma unroll
            for (int j = 0; j < 4; ++j) {
                int m = m0 + wr*64 + mi*16 + kq*4 + j;
                if (m >= M) continue;
                float v = acc[mi][ni][j];
                if (SCANEP) {
                    if (n < 512) {
                        v += bias[n];
                        v = fmaxf(v, 0.f) + log1pf(__expf(-fabsf(v)));
                        C[(size_t)m*ldc + n] = v;
                    } else {
                        bcbuf[(size_t)m*32 + (n - 512)] = v;
                    }
                } else {
                    if (HAS_BIAS) v += bv;
                    if (RELU) v = fmaxf(v, 0.f);
                    if (WF32) C[(size_t)m*ldc + n] = v;
                    if (W3)   pack_act(C3 + (size_t)m*(3*N_out), n, N_out, v);
                }
            }
        }
    }
}

// ---------------------------------------------------------------------------
// 5) conv + SiLU (fp32 xc + packed xc3), in-place silu on z-half of xz
// ---------------------------------------------------------------------------
__global__ __launch_bounds__(256)
void conv_silu(float* __restrict__ xz, const float* __restrict__ cw,
               const float* __restrict__ cb, float* __restrict__ xc,
               ushort* __restrict__ xc3, int rev)
{
    int idx = blockIdx.x * 256 + threadIdx.x;
    int d  = idx & (DD-1);
    int bt = idx >> 9;
    int t  = bt % TT;
    float cur = xz[(size_t)bt*2*DD + d];
    int tn = rev ? t + 1 : t - 1;
    float prev = 0.f;
    if (tn >= 0 && tn < TT)
        prev = xz[((size_t)bt + (rev ? 1 : -1))*2*DD + d];
    float v = prev*cw[d*2] + cur*cw[d*2+1] + cb[d];
    float sv = v / (1.f + __expf(-v));
    xc[idx] = sv;
    pack_act(xc3 + (size_t)bt*1536, d, 512, sv);
    float z = xz[(size_t)bt*2*DD + DD + d];
    xz[(size_t)bt*2*DD + DD + d] = z / (1.f + __expf(-z));
}

// ---------------------------------------------------------------------------
// 6) Scan V3: LDS-chunked, fixed-count unrolled inner loop.
//    block=(b, 64 d), 256 thr = 64 d x 4 s-groups.
// ---------------------------------------------------------------------------
#define CH 32
__global__ __launch_bounds__(256)
void scan2(const float* __restrict__ sp_g, const float* __restrict__ xc_g,
           const float* __restrict__ xz_g, const float* __restrict__ bc_g,
           const float* __restrict__ alog, const float* __restrict__ dparam,
           ushort* __restrict__ y3, int rev)
{
    int b  = blockIdx.x >> 3;
    int d0 = (blockIdx.x & 7) << 6;
    int tid = threadIdx.x;
    int sg = tid & 3;
    int dl = tid >> 2;
    int d  = d0 + dl;

    __shared__ float t_sp[CH][68], t_xc[CH][68], t_zs[CH][68], t_bc[CH][36];

    float Ac[4];
    #pragma unroll
    for (int j = 0; j < 4; ++j)
        Ac[j] = -__expf(alog[d*SS + sg*4 + j]);
    float dp = dparam[d];
    float h0=0.f, h1=0.f, h2=0.f, h3=0.f;
    size_t bbase = (size_t)b*TT;

    int r_a = tid >> 4, c_a = (tid & 15) << 2;
    int r_a2 = (tid + 256) >> 4, c_a2 = ((tid + 256) & 15) << 2;
    int r_b = tid >> 3, c_b = (tid & 7) << 2;

#define GROW(tg_) (rev ? (TT-1-(tg_)) : (tg_))
#define LOADCH(c_, s0,s1, x0,x1, z0,z1, bc0) { \
        int tgA = (c_)*CH + r_a;  if (tgA > TT-1) tgA = TT-1; \
        int tgB = (c_)*CH + r_a2; if (tgB > TT-1) tgB = TT-1; \
        int tgC = (c_)*CH + r_b;  if (tgC > TT-1) tgC = TT-1; \
        size_t pA = bbase + GROW(tgA), pB = bbase + GROW(tgB), pC = bbase + GROW(tgC); \
        s0 = *(const float4*)(sp_g + pA*DD + d0 + c_a); \
        s1 = *(const float4*)(sp_g + pB*DD + d0 + c_a2); \
        x0 = *(const float4*)(xc_g + pA*DD + d0 + c_a); \
        x1 = *(const float4*)(xc_g + pB*DD + d0 + c_a2); \
        z0 = *(const float4*)(xz_g + pA*2*DD + DD + d0 + c_a); \
        z1 = *(const float4*)(xz_g + pB*2*DD + DD + d0 + c_a2); \
        bc0 = *(const float4*)(bc_g + pC*32 + c_b); }

    float4 s0,s1,x0,x1,z0,z1,bc0;
    LOADCH(0, s0,s1,x0,x1,z0,z1,bc0);

    const int nch = (TT + CH - 1) / CH;
    for (int c = 0; c < nch; ++c) {
        __syncthreads();
        *(float4*)&t_sp[r_a ][c_a ] = s0;
        *(float4*)&t_sp[r_a2][c_a2] = s1;
        *(float4*)&t_xc[r_a ][c_a ] = x0;
        *(float4*)&t_xc[r_a2][c_a2] = x1;
        *(float4*)&t_zs[r_a ][c_a ] = z0;
        *(float4*)&t_zs[r_a2][c_a2] = z1;
        *(float4*)&t_bc[r_b ][c_b ] = bc0;
        if (c + 1 < nch)
            LOADCH(c+1, s0,s1,x0,x1,z0,z1,bc0);
        __syncthreads();

        int tbase = c*CH;
        #pragma unroll 4
        for (int i = 0; i < CH; ++i) {
            float spv = t_sp[i][dl];
            float xcv = t_xc[i][dl];
            float4 Bv = *(const float4*)&t_bc[i][sg*4];
            float4 Cv = *(const float4*)&t_bc[i][16 + sg*4];
            float dtxc = spv * xcv;
            float e0 = __expf(spv*Ac[0]);
            float e1 = __expf(spv*Ac[1]);
            float e2 = __expf(spv*Ac[2]);
            float e3 = __expf(spv*Ac[3]);
            h0 = fmaf(e0, h0, dtxc*Bv.x);
            h1 = fmaf(e1, h1, dtxc*Bv.y);
            h2 = fmaf(e2, h2, dtxc*Bv.z);
            h3 = fmaf(e3, h3, dtxc*Bv.w);
            float dot = h0*Cv.x + h1*Cv.y + h2*Cv.z + h3*Cv.w;
            dot += __shfl_xor(dot, 1);
            dot += __shfl_xor(dot, 2);
            int t = tbase + i;
            if (sg == 0 && t < TT) {
                int tg = GROW(t);
                float yv = (dot + dp*xcv) * t_zs[i][dl];
                pack_act(y3 + (bbase + tg)*1536, d, 512, yv);
            }
        }
    }
#undef LOADCH
#undef GROW
}

// ---------------------------------------------------------------------------
// 7) LayerNorm (up to 3 summed inputs), optional 3K-pack output
// ---------------------------------------------------------------------------
__global__ __launch_bounds__(64)
void ln_kernel(float* __restrict__ dst, const float* __restrict__ a,
               const float* __restrict__ b, const float* __restrict__ c,
               const float* __restrict__ g, const float* __restrict__ beta,
               ushort* __restrict__ out3)
{
    int row = blockIdx.x;
    int lane = threadIdx.x;
    size_t base = (size_t)row * DD;
    float x[8];
    #pragma unroll
    for (int j = 0; j < 2; ++j) {
        int e4 = j*64 + lane;
        float4 v = *(const float4*)(a + base + (size_t)e4*4);
        if (b) { float4 t = *(const float4*)(b + base + (size_t)e4*4); v.x+=t.x; v.y+=t.y; v.z+=t.z; v.w+=t.w; }
        if (c) { float4 t = *(const float4*)(c + base + (size_t)e4*4); v.x+=t.x; v.y+=t.y; v.z+=t.z; v.w+=t.w; }
        x[j*4+0]=v.x; x[j*4+1]=v.y; x[j*4+2]=v.z; x[j*4+3]=v.w;
    }
    float s = 0.f;
    #pragma unroll
    for (int i = 0; i < 8; ++i) s += x[i];
    #pragma unroll
    for (int m = 1; m < 64; m <<= 1) s += __shfl_xor(s, m);
    float mu = s * (1.f/DD);
    float vs = 0.f;
    #pragma unroll
    for (int i = 0; i < 8; ++i) { float dd = x[i]-mu; vs += dd*dd; }
    #pragma unroll
    for (int m = 1; m < 64; m <<= 1) vs += __shfl_xor(vs, m);
    float r = rsqrtf(vs*(1.f/DD) + 1e-5f);
    #pragma unroll
    for (int j = 0; j < 2; ++j) {
        int e4 = j*64 + lane;
        float4 gv = *(const float4*)(g    + (size_t)e4*4);
        float4 bv = *(const float4*)(beta + (size_t)e4*4);
        float4 o;
        o.x = (x[j*4+0]-mu)*r*gv.x + bv.x;
        o.y = (x[j*4+1]-mu)*r*gv.y + bv.y;
        o.z = (x[j*4+2]-mu)*r*gv.z + bv.z;
        o.w = (x[j*4+3]-mu)*r*gv.w + bv.w;
        *(float4*)(dst + base + (size_t)e4*4) = o;
        if (out3) {
            ushort* ob = out3 + (size_t)row*1536;
            pack_act(ob, e4*4+0, 512, o.x);
            pack_act(ob, e4*4+1, 512, o.y);
            pack_act(ob, e4*4+2, 512, o.z);
            pack_act(ob, e4*4+3, 512, o.w);
        }
    }
}

// ---------------------------------------------------------------------------
// 8) projection + transpose + de-norm
// ---------------------------------------------------------------------------
__global__ __launch_bounds__(128)
void proj_kernel(const float* __restrict__ hf, const float* __restrict__ pw,
                 const float* __restrict__ pb, const float* __restrict__ mean,
                 const float* __restrict__ stdv, float* __restrict__ out)
{
    int b  = blockIdx.x >> 5;
    int n0 = (blockIdx.x & 31) << 3;
    __shared__ float rows[8][DD];
    for (int i = threadIdx.x; i < 8*128; i += 128) {
        int rj = i >> 7, c4 = i & 127;
        ((float4*)rows[rj])[c4] =
            *(const float4*)(hf + ((size_t)b*TT + n0 + rj)*DD + (size_t)c4*4);
    }
    __syncthreads();
    int p = threadIdx.x;
    if (p < PRED) {
        float acc[8];
        #pragma unroll
        for (int j = 0; j < 8; ++j) acc[j] = 0.f;
        for (int k4 = 0; k4 < 128; ++k4) {
            float4 w = *(const float4*)(pw + (size_t)p*DD + (size_t)k4*4);
            #pragma unroll
            for (int j = 0; j < 8; ++j) {
                float4 rv = ((const float4*)rows[j])[k4];
                acc[j] += w.x*rv.x + w.y*rv.y + w.z*rv.z + w.w*rv.w;
            }
        }
        float bias = pb[p];
        #pragma unroll
        for (int j = 0; j < 8; ++j) {
            int n = n0 + j;
            out[((size_t)b*PRED + p)*NV + n] =
                (acc[j] + bias)*stdv[b*NV + n] + mean[b*NV + n];
        }
    }
}

// ---------------------------------------------------------------------------
extern "C" void kernel_launch(void* const* d_in, const int* in_sizes, int n_in,
                              void* d_out, int out_size, void* d_ws, size_t ws_size,
                              hipStream_t stream)
{
    (void)in_sizes; (void)n_in; (void)out_size; (void)ws_size;
    const float* x_enc   = (const float*)d_in[0];
    const float* x_mark  = (const float*)d_in[1];
    const float* emb_w   = (const float*)d_in[2];
    const float* emb_b   = (const float*)d_in[3];
    const float* m_win   = (const float*)d_in[4];
    const float* m_convw = (const float*)d_in[5];
    const float* m_convb = (const float*)d_in[6];
    const float* m_wx    = (const float*)d_in[7];
    const float* m_wdt   = (const float*)d_in[8];
    const float* m_bdt   = (const float*)d_in[9];
    const float* m_alog  = (const float*)d_in[10];
    const float* m_dpar  = (const float*)d_in[11];
    const float* m_wout  = (const float*)d_in[12];
    const float* ln1_g   = (const float*)d_in[13];
    const float* ln1_b   = (const float*)d_in[14];
    const float* ff1_w   = (const float*)d_in[15];
    const float* ff1_b   = (const float*)d_in[16];
    const float* ff2_w   = (const float*)d_in[17];
    const float* ff2_b   = (const float*)d_in[18];
    const float* ln2_g   = (const float*)d_in[19];
    const float* ln2_b   = (const float*)d_in[20];
    const float* lnf_g   = (const float*)d_in[21];
    const float* lnf_b   = (const float*)d_in[22];
    const float* proj_w  = (const float*)d_in[23];
    const float* proj_b  = (const float*)d_in[24];
    float* out = (float*)d_out;

    float* ws = (float*)d_ws;
    const size_t NBT = (size_t)MROWS;
    size_t off = 0;
    float* mean = ws + off; off += 8192;
    float* stdv = ws + off; off += 8192;
    ushort* w_emb3  = (ushort*)(ws + off); off += 393216;    // 512*1536 bf16
    ushort* w_win3  = (ushort*)(ws + off); off += 3145728;   // 4096*1536
    ushort* w_wout3 = (ushort*)(ws + off); off += 1572864;   // 2048*1536
    ushort* w_ff13  = (ushort*)(ws + off); off += 786432;    // 1024*1536
    ushort* w_ff23  = (ushort*)(ws + off); off += 786432;    // 1024*1536
    ushort* w_comb3 = (ushort*)(ws + off); off += 1671168;   // 4*544*1536
    ushort* tok3 = (ushort*)(ws + off); off += NBT*768;      // aliased: xc3, y3
    ushort* xc3 = tok3;
    ushort* y3  = tok3;
    float* h   = ws + off; off += NBT*DD;
    ushort* h3 = (ushort*)(ws + off); off += NBT*768;
    float* xz  = ws + off; off += NBT*2*DD;
    ushort* fft3 = (ushort*)xz;                              // alias (xz dead at ffn time)
    float* xc  = ws + off; off += NBT*DD;
    float* bc  = ws + off; off += NBT*32;
    float* sp  = ws + off; off += NBT*DD;
    float* fbuf = ws + off; off += NBT*DD;
    float* rbuf = ws + off; off += NBT*DD;

    // ---- weight packing (every call; deterministic) ----
    pack3w<<<dim3((512*512+255)/256),  256, 0, stream>>>(emb_w, w_emb3, 512*512);
    pack3w<<<dim3((4096*512+255)/256), 256, 0, stream>>>(m_win, w_win3, 4096*512);
    pack3w<<<dim3((2048*512+255)/256), 256, 0, stream>>>(m_wout, w_wout3, 2048*512);
    pack3w<<<dim3((1024*512+255)/256), 256, 0, stream>>>(ff1_w, w_ff13, 1024*512);
    pack3w<<<dim3((1024*512+255)/256), 256, 0, stream>>>(ff2_w, w_ff23, 1024*512);
    mkcomb<<<dim3(544,4), 256, 0, stream>>>(m_wx, m_wdt, w_comb3);

    stats_kernel<<<dim3(BB*4), 256, 0, stream>>>(x_enc, mean, stdv);
    tok_kernel<<<dim3(BB*40), 256, 0, stream>>>(x_enc, x_mark, mean, stdv, tok3);

    // h = tok @ emb_w.T + emb_b   (fp32 h + packed h3)
    gemm3<1,0,1,1,0><<<dim3(66,4), 256, 0, stream>>>(tok3, 1536, w_emb3, 1536,
        emb_b, h, DD, h3, DD, nullptr, MROWS, 512, 1536);

    for (int l = 0; l < 2; ++l) {
        for (int dir = 0; dir < 2; ++dir) {
            int li = l*2 + dir;
            gemm3<0,0,1,0,0><<<dim3(66,8), 256, 0, stream>>>(h3, 1536,
                w_win3 + (size_t)li*1024*1536, 1536, nullptr,
                xz, 2*DD, nullptr, 0, nullptr, MROWS, 1024, 1536);
            conv_silu<<<dim3((MROWS*DD)/256), 256, 0, stream>>>(
                xz, m_convw + (size_t)li*DD*2, m_convb + (size_t)li*DD,
                xc, xc3, dir);
            gemm3<0,0,0,0,1><<<dim3(66,5), 256, 0, stream>>>(xc3, 1536,
                w_comb3 + (size_t)li*544*1536, 1536, m_bdt + (size_t)li*DD,
                sp, 512, nullptr, 0, bc, MROWS, 544, 1536);
            scan2<<<dim3(BB*8), 256, 0, stream>>>(sp, xc, xz, bc,
                m_alog + (size_t)li*DD*SS, m_dpar + (size_t)li*DD, y3, dir);
            gemm3<0,0,1,0,0><<<dim3(66,4), 256, 0, stream>>>(y3, 1536,
                w_wout3 + (size_t)li*512*1536, 1536, nullptr,
                (dir == 0) ? fbuf : rbuf, DD, nullptr, 0, nullptr,
                MROWS, 512, 1536);
        }
        ln_kernel<<<dim3(MROWS), 64, 0, stream>>>(h, h, fbuf, rbuf,
            ln1_g + l*DD, ln1_b + l*DD, h3);
        gemm3<1,1,0,1,0><<<dim3(66,4), 256, 0, stream>>>(h3, 1536,
            w_ff13 + (size_t)l*512*1536, 1536, ff1_b + l*DD,
            nullptr, 0, fft3, DD, nullptr, MROWS, 512, 1536);
        gemm3<1,0,1,0,0><<<dim3(66,4), 256, 0, stream>>>(fft3, 1536,
            w_ff23 + (size_t)l*512*1536, 1536, ff2_b + l*DD,
            xc, DD, nullptr, 0, nullptr, MROWS, 512, 1536);
        ln_kernel<<<dim3(MROWS), 64, 0, stream>>>(h, h, xc, nullptr,
            ln2_g + l*DD, ln2_b + l*DD, h3);
    }
    ln_kernel<<<dim3(MROWS), 64, 0, stream>>>(fbuf, h, nullptr, nullptr,
                                              lnf_g, lnf_b, nullptr);
    proj_kernel<<<dim3(BB*32), 128, 0, stream>>>(fbuf, proj_w, proj_b, mean, stdv, out);
}